// Round 1
// baseline (157808.948 us; speedup 1.0000x reference)
//
#include <hip/hip_runtime.h>

#define DEV __device__ __forceinline__

namespace {
constexpr int NWG = 256, NTH = 256;
constexpr int Bc = 32, TENC = 512, TDECc = 512, Dc = 512, MELc = 80, KWc = 31;
constexpr int G4 = 2048;                 // 4*D gates
constexpr int KA = MELc + 2 * Dc;        // 1104: [mel(80); ctx(512); h_att(512)]
constexpr int KD = 3 * Dc;               // 1536: [h_att; ctx; h_dec]

// workspace layout in floats. Mutable (memset-zeroed) region first.
constexpr size_t OFF_S    = 16;                                  // [2][32] softmax denom
constexpr size_t OFF_W    = 96;                                  // [2][32][512] exp(e)
constexpr size_t OFF_ACUM = OFF_W    + (size_t)2 * Bc * TENC;    // [2][32][512]
constexpr size_t OFF_CTXT = OFF_ACUM + (size_t)2 * Bc * TENC;    // [2][512][32] unnormalized ctx^T
constexpr size_t OFF_HATT = OFF_CTXT + (size_t)2 * Dc * Bc;      // [2][512][32]
constexpr size_t OFF_HDEC = OFF_HATT + (size_t)2 * Dc * Bc;      // [2][512][32]
constexpr size_t OFF_CATT = OFF_HDEC + (size_t)2 * Dc * Bc;      // [512][32]
constexpr size_t OFF_CDEC = OFF_CATT + (size_t)Dc * Bc;          // [512][32]
constexpr size_t OFF_Q    = OFF_CDEC + (size_t)Dc * Bc;          // [32][512]
constexpr size_t ZERO_END = OFF_Q    + (size_t)Bc * Dc;
// read-only-after-INIT region
constexpr size_t OFF_MPROJ = (ZERO_END + 255) & ~(size_t)255;    // [32][512][512] (b,d,t)
constexpr size_t OFF_WATT  = OFF_MPROJ + (size_t)Bc * Dc * TENC; // [1104][2048]
constexpr size_t OFF_WDEC  = OFF_WATT  + (size_t)KA * G4;        // [1536][2048]
constexpr size_t OFF_WQT   = OFF_WDEC  + (size_t)KD * G4;        // [512][512]
constexpr size_t OFF_WMELT = OFF_WQT   + (size_t)Dc * Dc;        // [512][80]
constexpr size_t OFF_MELT  = OFF_WMELT + (size_t)Dc * MELc;      // [512][80][32]
constexpr size_t OFF_BA    = OFF_MELT  + (size_t)TDECc * MELc * Bc; // [2048]
constexpr size_t OFF_BD    = OFF_BA + G4;                        // [2048]
} // namespace

// device-coherent (L3-direct, sc1) accessors for mutable cross-WG state
DEV float ldg_(const float* p) { return __hip_atomic_load((float*)p, __ATOMIC_RELAXED, __HIP_MEMORY_SCOPE_AGENT); }
DEV void  stg_(float* p, float x) { __hip_atomic_store(p, x, __ATOMIC_RELAXED, __HIP_MEMORY_SCOPE_AGENT); }
DEV void  atadd_(float* p, float x) { (void)__hip_atomic_fetch_add(p, x, __ATOMIC_RELAXED, __HIP_MEMORY_SCOPE_AGENT); }
DEV float sigf(float x) { return 1.0f / (1.0f + __expf(-x)); }
DEV float tanhf2(float x) { return 1.0f - 2.0f / (__expf(2.0f * x) + 1.0f); }

union SharedU {
  struct { float x[KD][8]; float g[2][32][8]; float rs[8]; } pa;        // ~51 KB
  struct { float ain[96], acin[96], q[Dc], red[NTH], we[64]; } p2;      // ~4 KB
  struct { float ta[64][68], tw[64][68]; } init;                        // ~35 KB
  struct { float h[Dc]; } pb;
};

__global__ __launch_bounds__(NTH, 1) void decoder_persist(
    const float* __restrict__ enc, const float* __restrict__ mel_in,
    const float* __restrict__ Wih_att, const float* __restrict__ Whh_att, const float* __restrict__ b_att,
    const float* __restrict__ Wih_dec, const float* __restrict__ Whh_dec, const float* __restrict__ b_dec,
    const float* __restrict__ Wq, const float* __restrict__ Wm, const float* __restrict__ Wloc,
    const float* __restrict__ v, const float* __restrict__ Wmel, const float* __restrict__ bmel,
    const float* __restrict__ Wstop, const float* __restrict__ bstop,
    float* __restrict__ out, float* __restrict__ ws)
{
  const int wg = blockIdx.x, tid = threadIdx.x;
  __shared__ SharedU sh;

  unsigned int* bar = (unsigned int*)(ws);           // [0]=cnt, [1]=gen (memset to 0 pre-launch)
  float* S  = ws + OFF_S;   float* Wb = ws + OFF_W;   float* AC = ws + OFF_ACUM;
  float* CT = ws + OFF_CTXT; float* HA = ws + OFF_HATT; float* HD = ws + OFF_HDEC;
  float* CA = ws + OFF_CATT; float* CD = ws + OFF_CDEC; float* Q  = ws + OFF_Q;
  float* MP = ws + OFF_MPROJ; float* WA = ws + OFF_WATT; float* WD = ws + OFF_WDEC;
  float* WQT = ws + OFF_WQT; float* WMT = ws + OFF_WMELT; float* MT = ws + OFF_MELT;
  float* BA = ws + OFF_BA;  float* BD = ws + OFF_BD;

  // ---- grid barrier (generation counter; RELAXED spin so no L2 invalidation) ----
  auto gbar = [&]() {
    __syncthreads();
    if (tid == 0) {
      unsigned g = __hip_atomic_load(&bar[1], __ATOMIC_RELAXED, __HIP_MEMORY_SCOPE_AGENT);
      unsigned a = __hip_atomic_fetch_add(&bar[0], 1u, __ATOMIC_RELEASE, __HIP_MEMORY_SCOPE_AGENT);
      if (a == (unsigned)NWG - 1) {
        __hip_atomic_store(&bar[0], 0u, __ATOMIC_RELAXED, __HIP_MEMORY_SCOPE_AGENT);
        __hip_atomic_fetch_add(&bar[1], 1u, __ATOMIC_RELEASE, __HIP_MEMORY_SCOPE_AGENT);
      } else {
        while (__hip_atomic_load(&bar[1], __ATOMIC_RELAXED, __HIP_MEMORY_SCOPE_AGENT) == g)
          __builtin_amdgcn_s_sleep(8);
      }
    }
    __syncthreads();
  };

  // ================= INIT =================
  {
    // W_att transposed+gate-interleaved: WA[k][c], c = u*4+type  <->  row = type*512+u
    for (int k = wg; k < KA; k += NWG)
      for (int c = tid; c < G4; c += NTH) {
        int u = c >> 2, ty = c & 3, row = ty * Dc + u;
        float val = (k < MELc + Dc) ? Wih_att[(size_t)row * (MELc + Dc) + k]
                                    : Whh_att[(size_t)row * Dc + (k - (MELc + Dc))];
        stg_(WA + (size_t)k * G4 + c, val);
      }
    for (int k = wg; k < KD; k += NWG)
      for (int c = tid; c < G4; c += NTH) {
        int u = c >> 2, ty = c & 3, row = ty * Dc + u;
        float val = (k < 2 * Dc) ? Wih_dec[(size_t)row * (2 * Dc) + k]
                                 : Whh_dec[(size_t)row * Dc + (k - 2 * Dc)];
        stg_(WD + (size_t)k * G4 + c, val);
      }
    for (int k = wg; k < Dc; k += NWG)
      for (int d = tid; d < Dc; d += NTH) stg_(WQT + (size_t)k * Dc + d, Wq[(size_t)d * Dc + k]);
    if (wg == 0)
      for (int i = tid; i < Dc * MELc; i += NTH) { int k = i / MELc, m = i % MELc; stg_(WMT + (size_t)k * MELc + m, Wmel[(size_t)m * Dc + k]); }
    if (wg == 1)
      for (int c = tid; c < G4; c += NTH) { int u = c >> 2, ty = c & 3; stg_(BA + c, b_att[ty * Dc + u]); stg_(BD + c, b_dec[ty * Dc + u]); }
    if (wg == 2 && tid < Bc) stg_(S + 32 + tid, 1.0f);   // s[parity 1] = 1 (avoids 0/0 at step 0)
    // mel_in transposed: MT[t][m][b]
    for (int t = wg; t < TDECc; t += NWG)
      for (int i = tid; i < MELc * Bc; i += NTH) {
        int m = i >> 5, b = i & 31;
        stg_(MT + (size_t)t * MELc * Bc + m * Bc + b, mel_in[(size_t)b * TDECc * MELc + (size_t)t * MELc + m]);
      }
    // m_projT[b][d][t] = sum_k Wm[d][k] * enc[b][t][k]   (tiled fp32 GEMM)
    for (int tt = wg; tt < 2048; tt += NWG) {
      int b = tt >> 6, r = tt & 63, d0 = (r >> 3) * 64, t0 = (r & 7) * 64;
      float acc[4][4] = {};
      for (int kc = 0; kc < Dc; kc += 64) {
        __syncthreads();
        for (int i = tid; i < 64 * 64; i += NTH) {
          int rr = i >> 6, kk = i & 63;
          sh.init.tw[rr][kk] = Wm[(size_t)(d0 + rr) * Dc + kc + kk];
          sh.init.ta[rr][kk] = enc[((size_t)b * TENC + t0 + rr) * Dc + kc + kk];
        }
        __syncthreads();
        int tx = tid & 15, ty2 = tid >> 4;
        for (int kk = 0; kk < 64; ++kk) {
          float wv[4], ev[4];
#pragma unroll
          for (int p = 0; p < 4; ++p) { wv[p] = sh.init.tw[ty2 * 4 + p][kk]; ev[p] = sh.init.ta[tx * 4 + p][kk]; }
#pragma unroll
          for (int p = 0; p < 4; ++p)
#pragma unroll
            for (int q2 = 0; q2 < 4; ++q2) acc[p][q2] += wv[p] * ev[q2];
        }
      }
      int tx = tid & 15, ty2 = tid >> 4;
      for (int p = 0; p < 4; ++p)
        for (int q2 = 0; q2 < 4; ++q2)
          stg_(MP + ((size_t)b * Dc + d0 + ty2 * 4 + p) * TENC + t0 + tx * 4 + q2, acc[p][q2]);
    }
  }

  // ---- PA: att-LSTM for step n+1 and dec-LSTM for step n (gate GEMMs + cell update) ----
  auto PA = [&](int n, bool att_on, bool dec_on) {
    const int bg = wg >> 6, cg = wg & 63;
    const int cur = n & 1, nxt = 1 - (n & 1);
    if (tid < 8) sh.pa.rs[tid] = 1.0f / ldg_(S + cur * 32 + bg * 8 + tid);
    __syncthreads();
    const int bl = tid >> 5, cl = tid & 31;
    const int b = bg * 8 + bl;
    if (att_on) {
      for (int i = tid; i < KA * 8; i += NTH) {
        int k = i >> 3, l = i & 7, bb = bg * 8 + l; float val;
        if (k < MELc)            val = MT[(size_t)(n + 1) * MELc * Bc + k * Bc + bb];
        else if (k < MELc + Dc)  val = ldg_(CT + (size_t)cur * Dc * Bc + (k - MELc) * Bc + bb) * sh.pa.rs[l];
        else                     val = ldg_(HA + (size_t)cur * Dc * Bc + (k - MELc - Dc) * Bc + bb);
        sh.pa.x[k][l] = val;
      }
      __syncthreads();
      int c = cg * 32 + cl;
      float acc = ldg_(BA + c);
#pragma unroll 8
      for (int k = 0; k < KA; ++k) acc += WA[(size_t)k * G4 + c] * sh.pa.x[k][bl];
      sh.pa.g[0][cl][bl] = acc;
      __syncthreads();
      if ((cl & 3) == 0) {
        int ul = cl >> 2, u = cg * 8 + ul;
        float gi = sh.pa.g[0][ul * 4 + 0][bl], gf = sh.pa.g[0][ul * 4 + 1][bl];
        float gg = sh.pa.g[0][ul * 4 + 2][bl], go = sh.pa.g[0][ul * 4 + 3][bl];
        float co = CA[u * Bc + b];                       // WG-private across steps
        float cn = sigf(gf) * co + sigf(gi) * tanhf2(gg);
        CA[u * Bc + b] = cn;
        stg_(HA + (size_t)nxt * Dc * Bc + u * Bc + b, sigf(go) * tanhf2(cn));
      }
      __syncthreads();
    }
    if (dec_on) {
      for (int i = tid; i < KD * 8; i += NTH) {
        int k = i >> 3, l = i & 7, bb = bg * 8 + l; float val;
        if (k < Dc)          val = ldg_(HA + (size_t)cur * Dc * Bc + k * Bc + bb);
        else if (k < 2 * Dc) val = ldg_(CT + (size_t)cur * Dc * Bc + (k - Dc) * Bc + bb) * sh.pa.rs[l];
        else                 val = ldg_(HD + (size_t)nxt * Dc * Bc + (k - 2 * Dc) * Bc + bb);
        sh.pa.x[k][l] = val;
      }
      __syncthreads();
      int c = cg * 32 + cl;
      float acc = ldg_(BD + c);
#pragma unroll 8
      for (int k = 0; k < KD; ++k) acc += WD[(size_t)k * G4 + c] * sh.pa.x[k][bl];
      sh.pa.g[1][cl][bl] = acc;
      __syncthreads();
      if ((cl & 3) == 0) {
        int ul = cl >> 2, u = cg * 8 + ul;
        float gi = sh.pa.g[1][ul * 4 + 0][bl], gf = sh.pa.g[1][ul * 4 + 1][bl];
        float gg = sh.pa.g[1][ul * 4 + 2][bl], go = sh.pa.g[1][ul * 4 + 3][bl];
        float co = CD[u * Bc + b];
        float cn = sigf(gf) * co + sigf(gi) * tanhf2(gg);
        CD[u * Bc + b] = cn;
        stg_(HD + (size_t)cur * Dc * Bc + u * Bc + b, sigf(go) * tanhf2(cn));
      }
    }
  };

  // ---- P2: location conv + energies + exp + partial softmax-denominator + partial ctx ----
  auto P2 = [&](int n) {
    const int cur = n & 1, prv = 1 - (n & 1);
    const int b = wg & 31, j = wg >> 5, t0 = j * 64;
    if (tid < 94) {
      int g = t0 - 15 + tid;
      bool ok = (g >= 0 && g < TENC);
      float rsp = 1.0f / ldg_(S + prv * 32 + b);
      float av = ok ? ldg_(Wb + (size_t)prv * Bc * TENC + b * TENC + g) * rsp : 0.0f;
      float ac = (ok ? ldg_(AC + (size_t)prv * Bc * TENC + b * TENC + g) : 0.0f) + av;
      sh.p2.ain[tid] = av; sh.p2.acin[tid] = ac;
    }
    for (int k = tid; k < Dc; k += NTH) sh.p2.q[k] = ldg_(Q + (size_t)b * Dc + k);
    __syncthreads();
    if (tid < 64) stg_(AC + (size_t)cur * Bc * TENC + b * TENC + t0 + tid, sh.p2.acin[tid + 15]);
    const int tl = tid & 63;
    const int dcv = __builtin_amdgcn_readfirstlane(tid >> 6);   // wave-uniform d-chunk
    float aw[KWc], cw[KWc];
#pragma unroll
    for (int k = 0; k < KWc; ++k) { aw[k] = sh.p2.ain[tl + k]; cw[k] = sh.p2.acin[tl + k]; }
    float epart = 0.0f;
#pragma unroll 1
    for (int dd = 0; dd < 128; ++dd) {
      int d = dcv * 128 + dd;
      const float* wr = Wloc + d * 62;           // uniform address -> s_load
      float loc = 0.0f;
#pragma unroll
      for (int k = 0; k < KWc; ++k) loc += wr[k] * aw[k];
#pragma unroll
      for (int k = 0; k < KWc; ++k) loc += wr[KWc + k] * cw[k];
      float arg = sh.p2.q[d] + loc + MP[((size_t)b * Dc + d) * TENC + t0 + tl];
      epart += v[d] * tanhf2(arg);
    }
    sh.p2.red[tid] = epart;
    __syncthreads();
    if (tid < 64) {
      float e = sh.p2.red[tid] + sh.p2.red[tid + 64] + sh.p2.red[tid + 128] + sh.p2.red[tid + 192];
      float ex = __expf(e);                      // |e| <~ 20, safe without max-subtraction
      stg_(Wb + (size_t)cur * Bc * TENC + b * TENC + t0 + tid, ex);
      sh.p2.we[tid] = ex;
      float sum = ex;
#pragma unroll
      for (int off = 32; off > 0; off >>= 1) sum += __shfl_down(sum, off, 64);
      if (tid == 0) atadd_(S + cur * 32 + b, sum);
    }
    __syncthreads();
    for (int d2 = tid; d2 < Dc; d2 += NTH) {
      float cp = 0.0f;
#pragma unroll 4
      for (int t2 = 0; t2 < 64; ++t2) cp += sh.p2.we[t2] * enc[((size_t)b * TENC + t0 + t2) * Dc + d2];
      atadd_(CT + (size_t)cur * Dc * Bc + d2 * Bc + b, cp);
    }
  };

  // ---- PB: q_{n+1} = Wq@h_att_{n+1}; mel/stop outputs of step n; zero next accumulators ----
  auto PB = [&](int n) {
    const int cur = n & 1, nxt = 1 - (n & 1);
    if (wg < 64) {
      if (n < TDECc - 1) {
        int b = wg >> 1;
        for (int k = tid; k < Dc; k += NTH) sh.pb.h[k] = ldg_(HA + (size_t)nxt * Dc * Bc + k * Bc + b);
        __syncthreads();
        int d = (wg & 1) * 256 + tid;
        float acc = 0.0f;
#pragma unroll 8
        for (int k = 0; k < Dc; ++k) acc += WQT[(size_t)k * Dc + d] * sh.pb.h[k];
        stg_(Q + (size_t)b * Dc + d, acc);
      }
    } else if (wg < 74) {
      if (n >= 0) {
        int b2 = tid & 31, m = (wg - 64) * 8 + (tid >> 5);
        float acc = bmel[m];
#pragma unroll 4
        for (int k = 0; k < Dc; ++k) acc += WMT[(size_t)k * MELc + m] * ldg_(HD + (size_t)cur * Dc * Bc + k * Bc + b2);
        out[(size_t)b2 * TDECc * MELc + (size_t)n * MELc + m] = acc;
      }
    } else if (wg == 74) {
      if (n >= 0 && tid < Bc) {
        float acc = bstop[0];
#pragma unroll 4
        for (int k = 0; k < Dc; ++k) acc += Wstop[k] * ldg_(HD + (size_t)cur * Dc * Bc + k * Bc + tid);
        out[(size_t)Bc * TDECc * MELc + (size_t)tid * TDECc + n] = acc;
      }
    } else if (wg < 80) {
      for (int i = (wg - 75) * NTH + tid; i < Dc * Bc; i += 5 * NTH) stg_(CT + (size_t)nxt * Dc * Bc + i, 0.0f);
      if (wg == 75 && tid < Bc) stg_(S + nxt * 32 + tid, 0.0f);
    }
  };

  // ================= schedule =================
  gbar();
  PA(-1, true, false);   // att-LSTM step 0 (ctx=0, h=c=0)
  gbar();
  PB(-1);                // q_0; zero ctxT[0], s[0]
  gbar();
#pragma unroll 1
  for (int n = 0; n < TDECc; ++n) {
    P2(n); gbar();
    PA(n, n < TDECc - 1, true); gbar();
    PB(n); gbar();
  }
}

extern "C" void kernel_launch(void* const* d_in, const int* in_sizes, int n_in,
                              void* d_out, int out_size, void* d_ws, size_t ws_size,
                              hipStream_t stream) {
  (void)in_sizes; (void)n_in; (void)out_size; (void)ws_size;
  const float* enc     = (const float*)d_in[0];
  const float* mel_in  = (const float*)d_in[1];
  const float* Wih_att = (const float*)d_in[2];
  const float* Whh_att = (const float*)d_in[3];
  const float* b_att   = (const float*)d_in[4];
  const float* Wih_dec = (const float*)d_in[5];
  const float* Whh_dec = (const float*)d_in[6];
  const float* b_dec   = (const float*)d_in[7];
  const float* Wq      = (const float*)d_in[8];
  const float* Wm      = (const float*)d_in[9];
  const float* Wloc    = (const float*)d_in[10];
  const float* v       = (const float*)d_in[11];
  const float* Wmel    = (const float*)d_in[12];
  const float* bmel    = (const float*)d_in[13];
  const float* Wstop   = (const float*)d_in[14];
  const float* bstop   = (const float*)d_in[15];
  float* out = (float*)d_out;
  float* ws  = (float*)d_ws;

  // zero the barrier + mutable-state region (ws is re-poisoned before every call)
  hipMemsetAsync(d_ws, 0, ZERO_END * sizeof(float), stream);

  void* args[] = { &enc, &mel_in, &Wih_att, &Whh_att, &b_att, &Wih_dec, &Whh_dec, &b_dec,
                   &Wq, &Wm, &Wloc, &v, &Wmel, &bmel, &Wstop, &bstop, &out, &ws };
  hipLaunchCooperativeKernel((void*)decoder_persist, dim3(NWG), dim3(NTH), args, 0, stream);
}

// Round 2
// 78846.729 us; speedup vs baseline: 2.0015x; 2.0015x over previous
//
#include <hip/hip_runtime.h>

#define DEV __device__ __forceinline__

namespace {
constexpr int NWG = 256, NTH = 1024;
constexpr int Bc = 32, TENC = 512, TDECc = 512, Dc = 512, MELc = 80, KWc = 31;
constexpr int G4 = 2048;                 // 4*D gates
constexpr int KA = MELc + 2 * Dc;        // 1104
constexpr int KD = 3 * Dc;               // 1536

// workspace layout in floats. Mutable (memset-zeroed) region first.
// [0,640) = barrier: gen @0; arrival cells @ 64 + (parity*8+i)*32
constexpr size_t OFF_S    = 640;                                 // [2][32] softmax denom
constexpr size_t OFF_W    = OFF_S + 64;                          // [2][32][512] exp(e)
constexpr size_t OFF_ACUM = OFF_W    + (size_t)2 * Bc * TENC;    // [2][32][512]
constexpr size_t OFF_CTXT = OFF_ACUM + (size_t)2 * Bc * TENC;    // [2][512][32] unnormalized ctx^T
constexpr size_t OFF_HATT = OFF_CTXT + (size_t)2 * Dc * Bc;      // [2][512][32]
constexpr size_t OFF_HDEC = OFF_HATT + (size_t)2 * Dc * Bc;      // [2][512][32]
constexpr size_t OFF_CATT = OFF_HDEC + (size_t)2 * Dc * Bc;      // [512][32]
constexpr size_t OFF_CDEC = OFF_CATT + (size_t)Dc * Bc;          // [512][32]
constexpr size_t OFF_Q    = OFF_CDEC + (size_t)Dc * Bc;          // [32][512]
constexpr size_t ZERO_END = OFF_Q    + (size_t)Bc * Dc;
// read-only-after-INIT region
constexpr size_t OFF_MPROJ = (ZERO_END + 255) & ~(size_t)255;    // [32][512][512] (b,d,t)
constexpr size_t OFF_WATT  = OFF_MPROJ + (size_t)Bc * Dc * TENC; // [1104][2048]
constexpr size_t OFF_WDEC  = OFF_WATT  + (size_t)KA * G4;        // [1536][2048]
constexpr size_t OFF_WQT   = OFF_WDEC  + (size_t)KD * G4;        // [512][512]
constexpr size_t OFF_WMELT = OFF_WQT   + (size_t)Dc * Dc;        // [512][80]
constexpr size_t OFF_MELT  = OFF_WMELT + (size_t)Dc * MELc;      // [512][80][32]
constexpr size_t OFF_BA    = OFF_MELT  + (size_t)TDECc * MELc * Bc; // [2048]
constexpr size_t OFF_BD    = OFF_BA + G4;                        // [2048]
} // namespace

// device-coherent (L3-direct) accessors for mutable cross-WG state
DEV float ldg_(const float* p) { return __hip_atomic_load((float*)p, __ATOMIC_RELAXED, __HIP_MEMORY_SCOPE_AGENT); }
DEV void  stg_(float* p, float x) { __hip_atomic_store(p, x, __ATOMIC_RELAXED, __HIP_MEMORY_SCOPE_AGENT); }
DEV void  atadd_(float* p, float x) { (void)__hip_atomic_fetch_add(p, x, __ATOMIC_RELAXED, __HIP_MEMORY_SCOPE_AGENT); }
DEV float sigf(float x) { return 1.0f / (1.0f + __expf(-x)); }
DEV float tanhf2(float x) { return 1.0f - 2.0f / (__expf(2.0f * x) + 1.0f); }

union SharedU {
  struct { float x[KD][8]; float part[32][8][4]; float rs[8]; } pa;     // ~53 KB
  struct { float ain[96], acin[96], q[Dc], red[NTH], we[64]; } p2;      // ~7 KB
  struct { float ta[64][68], tw[64][68]; } init;                        // ~35 KB
  struct { float h[Dc]; float part[256][4]; float sp[32][33]; } pb;     // ~10 KB
};

__global__ __launch_bounds__(NTH, 4) void decoder_persist(
    const float* __restrict__ enc, const float* __restrict__ mel_in,
    const float* __restrict__ Wih_att, const float* __restrict__ Whh_att, const float* __restrict__ b_att,
    const float* __restrict__ Wih_dec, const float* __restrict__ Whh_dec, const float* __restrict__ b_dec,
    const float* __restrict__ Wq, const float* __restrict__ Wm, const float* __restrict__ Wloc,
    const float* __restrict__ v, const float* __restrict__ Wmel, const float* __restrict__ bmel,
    const float* __restrict__ Wstop, const float* __restrict__ bstop,
    float* __restrict__ out, float* __restrict__ ws)
{
  const int wg = blockIdx.x, tid = threadIdx.x;
  __shared__ SharedU sh;

  unsigned int* bar = (unsigned int*)(ws);           // gen @0; cells @64+(p*8+i)*32
  float* S  = ws + OFF_S;   float* Wb = ws + OFF_W;   float* AC = ws + OFF_ACUM;
  float* CT = ws + OFF_CTXT; float* HA = ws + OFF_HATT; float* HD = ws + OFF_HDEC;
  float* CA = ws + OFF_CATT; float* CD = ws + OFF_CDEC; float* Q  = ws + OFF_Q;
  float* MP = ws + OFF_MPROJ; float* WA = ws + OFF_WATT; float* WD = ws + OFF_WDEC;
  float* WQT = ws + OFF_WQT; float* WMT = ws + OFF_WMELT; float* MT = ws + OFF_MELT;
  float* BA = ws + OFF_BA;  float* BD = ws + OFF_BD;

  // ---- grid barrier: 8 padded arrival cells (parity-duplexed) + master poll ----
  auto gbar = [&]() {
    __syncthreads();
    if (tid == 0) {
      unsigned g = __hip_atomic_load(&bar[0], __ATOMIC_RELAXED, __HIP_MEMORY_SCOPE_AGENT);
      unsigned p = g & 1u;
      unsigned* cell = &bar[64 + (p * 8 + (wg & 7)) * 32];
      (void)__hip_atomic_fetch_add(cell, 1u, __ATOMIC_RELEASE, __HIP_MEMORY_SCOPE_AGENT);
      if (wg == 0) {
        for (;;) {
          unsigned s = 0;
#pragma unroll
          for (int i = 0; i < 8; ++i)
            s += __hip_atomic_load(&bar[64 + (p * 8 + i) * 32], __ATOMIC_RELAXED, __HIP_MEMORY_SCOPE_AGENT);
          if (s == (unsigned)NWG) break;
          __builtin_amdgcn_s_sleep(2);
        }
#pragma unroll
        for (int i = 0; i < 8; ++i)
          __hip_atomic_store(&bar[64 + (p * 8 + i) * 32], 0u, __ATOMIC_RELAXED, __HIP_MEMORY_SCOPE_AGENT);
        (void)__hip_atomic_fetch_add(&bar[0], 1u, __ATOMIC_RELEASE, __HIP_MEMORY_SCOPE_AGENT);
      } else {
        while (__hip_atomic_load(&bar[0], __ATOMIC_RELAXED, __HIP_MEMORY_SCOPE_AGENT) == g)
          __builtin_amdgcn_s_sleep(4);
      }
    }
    __syncthreads();
  };

  // ================= INIT =================
  {
    for (int k = wg; k < KA; k += NWG)
      for (int c = tid; c < G4; c += NTH) {
        int u = c >> 2, ty = c & 3, row = ty * Dc + u;
        float val = (k < MELc + Dc) ? Wih_att[(size_t)row * (MELc + Dc) + k]
                                    : Whh_att[(size_t)row * Dc + (k - (MELc + Dc))];
        stg_(WA + (size_t)k * G4 + c, val);
      }
    for (int k = wg; k < KD; k += NWG)
      for (int c = tid; c < G4; c += NTH) {
        int u = c >> 2, ty = c & 3, row = ty * Dc + u;
        float val = (k < 2 * Dc) ? Wih_dec[(size_t)row * (2 * Dc) + k]
                                 : Whh_dec[(size_t)row * Dc + (k - 2 * Dc)];
        stg_(WD + (size_t)k * G4 + c, val);
      }
    for (int k = wg; k < Dc; k += NWG)
      for (int d = tid; d < Dc; d += NTH) stg_(WQT + (size_t)k * Dc + d, Wq[(size_t)d * Dc + k]);
    if (wg == 0)
      for (int i = tid; i < Dc * MELc; i += NTH) { int k = i / MELc, m = i % MELc; stg_(WMT + (size_t)k * MELc + m, Wmel[(size_t)m * Dc + k]); }
    if (wg == 1)
      for (int c = tid; c < G4; c += NTH) { int u = c >> 2, ty = c & 3; stg_(BA + c, b_att[ty * Dc + u]); stg_(BD + c, b_dec[ty * Dc + u]); }
    if (wg == 2 && tid < Bc) stg_(S + 32 + tid, 1.0f);   // s[parity 1] = 1
    for (int t = wg; t < TDECc; t += NWG)
      for (int i = tid; i < MELc * Bc; i += NTH) {
        int m = i >> 5, b = i & 31;
        stg_(MT + (size_t)t * MELc * Bc + m * Bc + b, mel_in[(size_t)b * TDECc * MELc + (size_t)t * MELc + m]);
      }
    // m_projT[b][d][t] = sum_k Wm[d][k] * enc[b][t][k]
    for (int tt = wg; tt < 2048; tt += NWG) {
      int b = tt >> 6, r2 = tt & 63, d0 = (r2 >> 3) * 64, t0 = (r2 & 7) * 64;
      float acc[2][2] = {};
      for (int kc = 0; kc < Dc; kc += 64) {
        __syncthreads();
        for (int i = tid; i < 64 * 64; i += NTH) {
          int rr = i >> 6, kk = i & 63;
          sh.init.tw[rr][kk] = Wm[(size_t)(d0 + rr) * Dc + kc + kk];
          sh.init.ta[rr][kk] = enc[((size_t)b * TENC + t0 + rr) * Dc + kc + kk];
        }
        __syncthreads();
        int tx = tid & 31, ty2 = tid >> 5;  // 32 x 32, each 2x2
        for (int kk = 0; kk < 64; ++kk) {
          float wv[2], ev[2];
#pragma unroll
          for (int p = 0; p < 2; ++p) { wv[p] = sh.init.tw[ty2 * 2 + p][kk]; ev[p] = sh.init.ta[tx * 2 + p][kk]; }
#pragma unroll
          for (int p = 0; p < 2; ++p)
#pragma unroll
            for (int q2 = 0; q2 < 2; ++q2) acc[p][q2] += wv[p] * ev[q2];
        }
      }
      int tx = tid & 31, ty2 = tid >> 5;
      for (int p = 0; p < 2; ++p)
        for (int q2 = 0; q2 < 2; ++q2)
          stg_(MP + ((size_t)b * Dc + d0 + ty2 * 2 + p) * TENC + t0 + tx * 2 + q2, acc[p][q2]);
    }
  }

  // ---- PA: att-LSTM for step n+1 and dec-LSTM for step n (K-split 4-way) ----
  auto PA = [&](int n, bool att_on, bool dec_on) {
    const int bg = wg >> 6, cg = wg & 63;
    const int cur = n & 1, nxt = 1 - cur;
    if (tid < 8) sh.pa.rs[tid] = 1.0f / ldg_(S + cur * 32 + bg * 8 + tid);
    __syncthreads();
    const int ks = tid >> 8, r = tid & 255, bl = r >> 5, cl = r & 31;
    const int b = bg * 8 + bl, c = cg * 32 + cl;
    if (att_on) {
      for (int i = tid; i < KA * 8; i += NTH) {
        int k = i >> 3, l = i & 7, bb = bg * 8 + l; float val;
        if (k < MELc)            val = MT[(size_t)(n + 1) * MELc * Bc + k * Bc + bb];
        else if (k < MELc + Dc)  val = ldg_(CT + (size_t)cur * Dc * Bc + (k - MELc) * Bc + bb) * sh.pa.rs[l];
        else                     val = ldg_(HA + (size_t)cur * Dc * Bc + (k - MELc - Dc) * Bc + bb);
        sh.pa.x[k][l] = val;
      }
      __syncthreads();
      float acc = (ks == 3) ? ldg_(BA + c) : 0.0f;
      const int k0 = ks * (KA / 4), k1 = k0 + KA / 4;   // 276 each
#pragma unroll 4
      for (int k = k0; k < k1; ++k) acc += WA[(size_t)k * G4 + c] * sh.pa.x[k][bl];
      sh.pa.part[cl][bl][ks] = acc;
      __syncthreads();
      if (tid < 256 && (cl & 3) == 0) {
        int ul = cl >> 2, u = cg * 8 + ul;
        float g4[4];
#pragma unroll
        for (int t = 0; t < 4; ++t)
          g4[t] = sh.pa.part[ul * 4 + t][bl][0] + sh.pa.part[ul * 4 + t][bl][1]
                + sh.pa.part[ul * 4 + t][bl][2] + sh.pa.part[ul * 4 + t][bl][3];
        float co = CA[u * Bc + b];                       // WG-private across steps
        float cn = sigf(g4[1]) * co + sigf(g4[0]) * tanhf2(g4[2]);
        CA[u * Bc + b] = cn;
        stg_(HA + (size_t)nxt * Dc * Bc + u * Bc + b, sigf(g4[3]) * tanhf2(cn));
      }
      __syncthreads();
    }
    if (dec_on) {
      for (int i = tid; i < KD * 8; i += NTH) {
        int k = i >> 3, l = i & 7, bb = bg * 8 + l; float val;
        if (k < Dc)          val = ldg_(HA + (size_t)cur * Dc * Bc + k * Bc + bb);
        else if (k < 2 * Dc) val = ldg_(CT + (size_t)cur * Dc * Bc + (k - Dc) * Bc + bb) * sh.pa.rs[l];
        else                 val = ldg_(HD + (size_t)nxt * Dc * Bc + (k - 2 * Dc) * Bc + bb);
        sh.pa.x[k][l] = val;
      }
      __syncthreads();
      float acc = (ks == 3) ? ldg_(BD + c) : 0.0f;
      const int k0 = ks * (KD / 4), k1 = k0 + KD / 4;   // 384 each
#pragma unroll 4
      for (int k = k0; k < k1; ++k) acc += WD[(size_t)k * G4 + c] * sh.pa.x[k][bl];
      sh.pa.part[cl][bl][ks] = acc;
      __syncthreads();
      if (tid < 256 && (cl & 3) == 0) {
        int ul = cl >> 2, u = cg * 8 + ul;
        float g4[4];
#pragma unroll
        for (int t = 0; t < 4; ++t)
          g4[t] = sh.pa.part[ul * 4 + t][bl][0] + sh.pa.part[ul * 4 + t][bl][1]
                + sh.pa.part[ul * 4 + t][bl][2] + sh.pa.part[ul * 4 + t][bl][3];
        float co = CD[u * Bc + b];
        float cn = sigf(g4[1]) * co + sigf(g4[0]) * tanhf2(g4[2]);
        CD[u * Bc + b] = cn;
        stg_(HD + (size_t)cur * Dc * Bc + u * Bc + b, sigf(g4[3]) * tanhf2(cn));
      }
    }
  };

  // ---- P2: location conv + energies + softmax pieces + partial ctx ----
  auto P2 = [&](int n) {
    const int cur = n & 1, prv = 1 - cur;
    const int b = wg & 31, j = wg >> 5, t0 = j * 64;
    if (tid < 94) {
      int g = t0 - 15 + tid;
      bool ok = (g >= 0 && g < TENC);
      float rsp = 1.0f / ldg_(S + prv * 32 + b);
      float av = ok ? ldg_(Wb + (size_t)prv * Bc * TENC + b * TENC + g) * rsp : 0.0f;
      float ac = (ok ? ldg_(AC + (size_t)prv * Bc * TENC + b * TENC + g) : 0.0f) + av;
      sh.p2.ain[tid] = av; sh.p2.acin[tid] = ac;
    }
    for (int k = tid; k < Dc; k += NTH) sh.p2.q[k] = ldg_(Q + (size_t)b * Dc + k);
    __syncthreads();
    if (tid < 64) stg_(AC + (size_t)cur * Bc * TENC + b * TENC + t0 + tid, sh.p2.acin[tid + 15]);
    const int tl = tid & 63;
    const int dc = __builtin_amdgcn_readfirstlane(tid >> 6);   // wave-uniform d-chunk (0..15)
    float aw[KWc], cw[KWc];
#pragma unroll
    for (int k = 0; k < KWc; ++k) { aw[k] = sh.p2.ain[tl + k]; cw[k] = sh.p2.acin[tl + k]; }
    float epart = 0.0f;
#pragma unroll 2
    for (int dd = 0; dd < 32; ++dd) {
      int d = dc * 32 + dd;
      const float* wr = Wloc + d * 62;           // uniform address -> s_load
      float loc = 0.0f;
#pragma unroll
      for (int k = 0; k < KWc; ++k) loc += wr[k] * aw[k];
#pragma unroll
      for (int k = 0; k < KWc; ++k) loc += wr[KWc + k] * cw[k];
      float arg = sh.p2.q[d] + loc + MP[((size_t)b * Dc + d) * TENC + t0 + tl];
      epart += v[d] * tanhf2(arg);
    }
    sh.p2.red[tid] = epart;
    __syncthreads();
    if (tid < 64) {
      float e = 0.0f;
#pragma unroll
      for (int i = 0; i < 16; ++i) e += sh.p2.red[i * 64 + tl];
      float ex = __expf(e);
      stg_(Wb + (size_t)cur * Bc * TENC + b * TENC + t0 + tl, ex);
      sh.p2.we[tl] = ex;
      float sum = ex;
#pragma unroll
      for (int off = 32; off > 0; off >>= 1) sum += __shfl_down(sum, off, 64);
      if (tl == 0) atadd_(S + cur * 32 + b, sum);
    }
    __syncthreads();
    if (tid < Dc) {
      float cp = 0.0f;
#pragma unroll 4
      for (int t2 = 0; t2 < 64; ++t2) cp += sh.p2.we[t2] * enc[((size_t)b * TENC + t0 + t2) * Dc + tid];
      atadd_(CT + (size_t)cur * Dc * Bc + tid * Bc + b, cp);
    }
  };

  // ---- PB: q_{n+1}; mel/stop outputs of step n; zero next accumulators ----
  auto PB = [&](int n) {
    const int cur = n & 1, nxt = 1 - cur;
    if (wg < 64) {
      if (n < TDECc - 1) {
        int b = wg >> 1;
        for (int k = tid; k < Dc; k += NTH) sh.pb.h[k] = ldg_(HA + (size_t)nxt * Dc * Bc + k * Bc + b);
        __syncthreads();
        int ks = tid >> 8, dl = tid & 255, d = (wg & 1) * 256 + dl;
        float acc = 0.0f;
        const int k0 = ks * 128, k1 = k0 + 128;
#pragma unroll 4
        for (int k = k0; k < k1; ++k) acc += WQT[(size_t)k * Dc + d] * sh.pb.h[k];
        sh.pb.part[dl][ks] = acc;
        __syncthreads();
        if (tid < 256)
          stg_(Q + (size_t)b * Dc + (wg & 1) * 256 + tid,
               sh.pb.part[tid][0] + sh.pb.part[tid][1] + sh.pb.part[tid][2] + sh.pb.part[tid][3]);
      }
    } else if (wg < 74) {
      if (n >= 0) {
        int b2 = tid & 31, mq = tid >> 5, ml = mq & 7, ks = mq >> 3;
        int m = (wg - 64) * 8 + ml;
        float acc = (ks == 0) ? bmel[m] : 0.0f;
        const int k0 = ks * 128, k1 = k0 + 128;
#pragma unroll 4
        for (int k = k0; k < k1; ++k) acc += WMT[(size_t)k * MELc + m] * ldg_(HD + (size_t)cur * Dc * Bc + k * Bc + b2);
        sh.pb.part[(ml << 5) | b2][ks] = acc;
        __syncthreads();
        if (tid < 256) {
          int mm = (wg - 64) * 8 + (tid >> 5), bb = tid & 31;
          out[(size_t)bb * TDECc * MELc + (size_t)n * MELc + mm] =
              sh.pb.part[tid][0] + sh.pb.part[tid][1] + sh.pb.part[tid][2] + sh.pb.part[tid][3];
        }
      }
    } else if (wg == 74) {
      if (n >= 0) {
        int b2 = tid & 31, ks = tid >> 5;   // 32 chunks of 16
        float acc = (ks == 0) ? bstop[0] : 0.0f;
        const int k0 = ks * 16, k1 = k0 + 16;
#pragma unroll 4
        for (int k = k0; k < k1; ++k) acc += Wstop[k] * ldg_(HD + (size_t)cur * Dc * Bc + k * Bc + b2);
        sh.pb.sp[ks][b2] = acc;
        __syncthreads();
        if (tid < 32) {
          float s2 = 0.0f;
#pragma unroll
          for (int i = 0; i < 32; ++i) s2 += sh.pb.sp[i][tid];
          out[(size_t)Bc * TDECc * MELc + (size_t)tid * TDECc + n] = s2;
        }
      }
    } else if (wg < 80) {
      for (int i = (wg - 75) * NTH + tid; i < Dc * Bc; i += 5 * NTH) stg_(CT + (size_t)nxt * Dc * Bc + i, 0.0f);
      if (wg == 75 && tid < Bc) stg_(S + nxt * 32 + tid, 0.0f);
    }
  };

  // ================= schedule =================
  gbar();
  PA(-1, true, false);   // att-LSTM step 0 (ctx=0, h=c=0)
  gbar();
  PB(-1);                // q_0; zero ctxT[0], s[0]
  gbar();
#pragma unroll 1
  for (int n = 0; n < TDECc; ++n) {
    P2(n); gbar();
    PA(n, n < TDECc - 1, true); gbar();
    PB(n); gbar();
  }
}

extern "C" void kernel_launch(void* const* d_in, const int* in_sizes, int n_in,
                              void* d_out, int out_size, void* d_ws, size_t ws_size,
                              hipStream_t stream) {
  (void)in_sizes; (void)n_in; (void)out_size; (void)ws_size;
  const float* enc     = (const float*)d_in[0];
  const float* mel_in  = (const float*)d_in[1];
  const float* Wih_att = (const float*)d_in[2];
  const float* Whh_att = (const float*)d_in[3];
  const float* b_att   = (const float*)d_in[4];
  const float* Wih_dec = (const float*)d_in[5];
  const float* Whh_dec = (const float*)d_in[6];
  const float* b_dec   = (const float*)d_in[7];
  const float* Wq      = (const float*)d_in[8];
  const float* Wm      = (const float*)d_in[9];
  const float* Wloc    = (const float*)d_in[10];
  const float* v       = (const float*)d_in[11];
  const float* Wmel    = (const float*)d_in[12];
  const float* bmel    = (const float*)d_in[13];
  const float* Wstop   = (const float*)d_in[14];
  const float* bstop   = (const float*)d_in[15];
  float* out = (float*)d_out;
  float* ws  = (float*)d_ws;

  hipMemsetAsync(d_ws, 0, ZERO_END * sizeof(float), stream);

  void* args[] = { &enc, &mel_in, &Wih_att, &Whh_att, &b_att, &Wih_dec, &Whh_dec, &b_dec,
                   &Wq, &Wm, &Wloc, &v, &Wmel, &bmel, &Wstop, &bstop, &out, &ws };
  hipLaunchCooperativeKernel((void*)decoder_persist, dim3(NWG), dim3(NTH), args, 0, stream);
}

// Round 3
// 67757.812 us; speedup vs baseline: 2.3290x; 1.1637x over previous
//
#include <hip/hip_runtime.h>

#define DEV __device__ __forceinline__

typedef __attribute__((ext_vector_type(8))) short short8;   // 8 bf16 = 4 VGPR
typedef __attribute__((ext_vector_type(4))) float f32x4;

namespace {
constexpr int NWG = 256, NTH = 1024;
constexpr int Bc = 32, TENC = 512, TDECc = 512, Dc = 512, MELc = 80;

// ---- mutable (memset-zeroed) region, same as round 2 ----
constexpr size_t OFF_S    = 640;                                 // [2][32] softmax denom
constexpr size_t OFF_W    = OFF_S + 64;                          // [2][32][512] exp(e)
constexpr size_t OFF_ACUM = OFF_W    + (size_t)2 * Bc * TENC;    // [2][32][512]
constexpr size_t OFF_CTXT = OFF_ACUM + (size_t)2 * Bc * TENC;    // [2][512][32] unnormalized ctx^T
constexpr size_t OFF_HATT = OFF_CTXT + (size_t)2 * Dc * Bc;      // [2][512][32]
constexpr size_t OFF_HDEC = OFF_HATT + (size_t)2 * Dc * Bc;      // [2][512][32]
constexpr size_t OFF_CATT = OFF_HDEC + (size_t)2 * Dc * Bc;      // [512][32]
constexpr size_t OFF_CDEC = OFF_CATT + (size_t)Dc * Bc;          // [512][32]
constexpr size_t OFF_Q    = OFF_CDEC + (size_t)Dc * Bc;          // [32][512]
constexpr size_t ZERO_END = OFF_Q    + (size_t)Bc * Dc;
// ---- read-only after INIT / per-step rewritten ----
constexpr size_t OFF_MPROJ = (ZERO_END + 255) & ~(size_t)255;    // [32][512(t)][512(d)]
constexpr size_t OFF_WASW  = OFF_MPROJ + (size_t)Bc * TENC * Dc; // att A-frags [128][104][64][8] bf16
constexpr size_t OFF_WDSW  = OFF_WASW + (size_t)128*104*64*4;    // dec A-frags [128][144][64][8]
constexpr size_t OFF_WLSW  = OFF_WDSW + (size_t)128*144*64*4;    // conv A-frags [32][6][64][8]
constexpr size_t OFF_XSA   = OFF_WLSW + (size_t)32*6*64*4;       // att B-frags [104][2][64][8]
constexpr size_t OFF_XSD   = OFF_XSA + (size_t)104*2*64*4;       // dec B-frags [144][2][64][8]
constexpr size_t OFF_WQT   = OFF_XSD + (size_t)144*2*64*4;       // [512][512] fp32
constexpr size_t OFF_WMELT = OFF_WQT + (size_t)Dc*Dc;            // [512][80]
constexpr size_t OFF_MELT  = OFF_WMELT + (size_t)Dc*MELc;        // [512][80][32]
constexpr size_t OFF_BA    = OFF_MELT + (size_t)TDECc*MELc*Bc;   // [2048] interleaved c=u*4+ty
constexpr size_t OFF_BD    = OFF_BA + 2048;                      // [2048]
} // namespace

// device-coherent (L3-direct) accessors for mutable cross-WG state
DEV float ldg_(const float* p) { return __hip_atomic_load((float*)p, __ATOMIC_RELAXED, __HIP_MEMORY_SCOPE_AGENT); }
DEV void  stg_(float* p, float x) { __hip_atomic_store(p, x, __ATOMIC_RELAXED, __HIP_MEMORY_SCOPE_AGENT); }
DEV unsigned ldgu_(const unsigned* p) { return __hip_atomic_load((unsigned*)p, __ATOMIC_RELAXED, __HIP_MEMORY_SCOPE_AGENT); }
DEV void  stgu_(unsigned* p, unsigned x) { __hip_atomic_store(p, x, __ATOMIC_RELAXED, __HIP_MEMORY_SCOPE_AGENT); }
DEV void  atadd_(float* p, float x) { (void)__hip_atomic_fetch_add(p, x, __ATOMIC_RELAXED, __HIP_MEMORY_SCOPE_AGENT); }
DEV float sigf(float x) { return 1.0f / (1.0f + __expf(-x)); }
DEV float tanhf2(float x) { return 1.0f - 2.0f / (__expf(2.0f * x) + 1.0f); }
// bf16 RNE conversion helpers
DEV unsigned short bfh(float x) { union { float f; unsigned u; } v; v.f = x; unsigned r = v.u + 0x7FFF + ((v.u >> 16) & 1); return (unsigned short)(r >> 16); }
DEV float bf2f(unsigned short h) { union { unsigned u; float f; } v; v.u = (unsigned)h << 16; return v.f; }

union PK8 { unsigned short us[8]; short8 s8; unsigned u[4]; };

DEV void store_pk(unsigned short* dst, const PK8& pk) {
  unsigned* d = (unsigned*)dst;
#pragma unroll
  for (int i = 0; i < 4; ++i) stgu_(d + i, pk.u[i]);
}
DEV short8 load_pk(const unsigned short* src) {
  const unsigned* s = (const unsigned*)src;
  PK8 pk;
#pragma unroll
  for (int i = 0; i < 4; ++i) pk.u[i] = ldgu_(s + i);
  return pk.s8;
}

union SharedU {
  struct __attribute__((aligned(16))) {
    unsigned short win[12288];          // [nt4][ks6][lane64][8] B-frags, 24.6 KB
    float q[512], v[512];
    float ain[96], acin[96];
    float ered[16][64];
    float we[64];
  } t1;                                 // ~34 KB
  struct __attribute__((aligned(16))) { float red[16][2][64][4]; } gg;   // 32 KB
  struct { float ta[64][68], tw[64][68]; } init;                         // 34.8 KB
  struct { float h[512]; float part[256][4]; float sp[32][33]; } qm;     // ~10 KB
};

__global__ __launch_bounds__(NTH, 4) void decoder_persist(
    const float* __restrict__ enc, const float* __restrict__ mel_in,
    const float* __restrict__ Wih_att, const float* __restrict__ Whh_att, const float* __restrict__ b_att,
    const float* __restrict__ Wih_dec, const float* __restrict__ Whh_dec, const float* __restrict__ b_dec,
    const float* __restrict__ Wq, const float* __restrict__ Wm, const float* __restrict__ Wloc,
    const float* __restrict__ v, const float* __restrict__ Wmel, const float* __restrict__ bmel,
    const float* __restrict__ Wstop, const float* __restrict__ bstop,
    float* __restrict__ out, float* __restrict__ ws)
{
  const int wg = blockIdx.x, tid = threadIdx.x;
  __shared__ SharedU sh;

  unsigned int* bar = (unsigned int*)(ws);           // gen @0; cells @64+(p*8+i)*32
  float* S  = ws + OFF_S;   float* Wb = ws + OFF_W;   float* AC = ws + OFF_ACUM;
  float* CT = ws + OFF_CTXT; float* HA = ws + OFF_HATT; float* HD = ws + OFF_HDEC;
  float* CA = ws + OFF_CATT; float* CD = ws + OFF_CDEC; float* Q  = ws + OFF_Q;
  float* MP = ws + OFF_MPROJ;
  unsigned short* WASW = (unsigned short*)(ws + OFF_WASW);
  unsigned short* WDSW = (unsigned short*)(ws + OFF_WDSW);
  unsigned short* WLSW = (unsigned short*)(ws + OFF_WLSW);
  unsigned short* XSA  = (unsigned short*)(ws + OFF_XSA);
  unsigned short* XSD  = (unsigned short*)(ws + OFF_XSD);
  float* WQT = ws + OFF_WQT; float* WMT = ws + OFF_WMELT; float* MT = ws + OFF_MELT;
  float* BA = ws + OFF_BA;  float* BD = ws + OFF_BD;

  // ---- grid barrier: 8 padded arrival cells (parity-duplexed) + master poll ----
  auto gbar = [&]() {
    __syncthreads();
    if (tid == 0) {
      unsigned g = __hip_atomic_load(&bar[0], __ATOMIC_RELAXED, __HIP_MEMORY_SCOPE_AGENT);
      unsigned p = g & 1u;
      (void)__hip_atomic_fetch_add(&bar[64 + (p * 8 + (wg & 7)) * 32], 1u, __ATOMIC_RELEASE, __HIP_MEMORY_SCOPE_AGENT);
      if (wg == 0) {
        for (;;) {
          unsigned s = 0;
#pragma unroll
          for (int i = 0; i < 8; ++i)
            s += __hip_atomic_load(&bar[64 + (p * 8 + i) * 32], __ATOMIC_RELAXED, __HIP_MEMORY_SCOPE_AGENT);
          if (s == (unsigned)NWG) break;
          __builtin_amdgcn_s_sleep(2);
        }
#pragma unroll
        for (int i = 0; i < 8; ++i)
          __hip_atomic_store(&bar[64 + (p * 8 + i) * 32], 0u, __ATOMIC_RELAXED, __HIP_MEMORY_SCOPE_AGENT);
        (void)__hip_atomic_fetch_add(&bar[0], 1u, __ATOMIC_RELEASE, __HIP_MEMORY_SCOPE_AGENT);
      } else {
        while (__hip_atomic_load(&bar[0], __ATOMIC_RELAXED, __HIP_MEMORY_SCOPE_AGENT) == g)
          __builtin_amdgcn_s_sleep(4);
      }
    }
    __syncthreads();
  };

  // ================= INIT =================
  {
    // Wq^T, Wmel^T, biases (interleaved c=u*4+ty), S[parity1]=1, mel transposed
    for (int k = wg; k < Dc; k += NWG)
      for (int d = tid; d < Dc; d += NTH) stg_(WQT + (size_t)k * Dc + d, Wq[(size_t)d * Dc + k]);
    if (wg == 0)
      for (int i = tid; i < Dc * MELc; i += NTH) { int k = i / MELc, m = i % MELc; stg_(WMT + (size_t)k * MELc + m, Wmel[(size_t)m * Dc + k]); }
    if (wg == 1)
      for (int c = tid; c < 2048; c += NTH) { int u = c >> 2, ty = c & 3; stg_(BA + c, b_att[ty * Dc + u]); stg_(BD + c, b_dec[ty * Dc + u]); }
    if (wg == 2 && tid < Bc) stg_(S + 32 + tid, 1.0f);
    for (int t = wg; t < TDECc; t += NWG)
      for (int i = tid; i < MELc * Bc; i += NTH) {
        int m = i >> 5, b = i & 31;
        stg_(MT + (size_t)t * MELc * Bc + m * Bc + b, mel_in[(size_t)b * TDECc * MELc + (size_t)t * MELc + m]);
      }
    // att gate-weight A-frags, split-bf16 (3 groups of 1104, padded to 3328 = 104 ksteps)
    for (size_t id = (size_t)wg * NTH + tid; id < (size_t)128 * 104 * 64; id += (size_t)NWG * NTH) {
      int l = id & 63; size_t r = id >> 6; int ks = (int)(r % 104); int m = (int)(r / 104);
      int c = m * 16 + (l & 15), u = c >> 2, ty = c & 3, wrow = ty * 512 + u, koct = l >> 4;
      PK8 pk;
#pragma unroll
      for (int j = 0; j < 8; ++j) {
        int ke = ks * 32 + koct * 8 + j; float x = 0.0f; int g = 0;
        if (ke < 3312) {
          g = ke / 1104; int kk = ke - g * 1104;
          x = (kk < 592) ? Wih_att[(size_t)wrow * 592 + kk] : Whh_att[(size_t)wrow * 512 + (kk - 592)];
        }
        unsigned short hi = bfh(x);
        pk.us[j] = (g == 2) ? bfh(x - bf2f(hi)) : hi;
      }
      store_pk(WASW + id * 8, pk);
    }
    // dec gate-weight A-frags (3 groups of 1536 = 4608 = 144 ksteps, no pad)
    for (size_t id = (size_t)wg * NTH + tid; id < (size_t)128 * 144 * 64; id += (size_t)NWG * NTH) {
      int l = id & 63; size_t r = id >> 6; int ks = (int)(r % 144); int m = (int)(r / 144);
      int c = m * 16 + (l & 15), u = c >> 2, ty = c & 3, wrow = ty * 512 + u, koct = l >> 4;
      PK8 pk;
#pragma unroll
      for (int j = 0; j < 8; ++j) {
        int ke = ks * 32 + koct * 8 + j;
        int g = ke / 1536, kk = ke - g * 1536;
        float x = (kk < 1024) ? Wih_dec[(size_t)wrow * 1024 + kk] : Whh_dec[(size_t)wrow * 512 + (kk - 1024)];
        unsigned short hi = bfh(x);
        pk.us[j] = (g == 2) ? bfh(x - bf2f(hi)) : hi;
      }
      store_pk(WDSW + id * 8, pk);
    }
    // conv weight A-frags (3 groups padded to 64 each = 192 = 6 ksteps)
    for (size_t id = (size_t)wg * NTH + tid; id < (size_t)32 * 6 * 64; id += (size_t)NWG * NTH) {
      int l = id & 63; size_t r = id >> 6; int ks = (int)(r % 6); int mt = (int)(r / 6);
      int d = mt * 16 + (l & 15), koct = l >> 4;
      PK8 pk;
#pragma unroll
      for (int j = 0; j < 8; ++j) {
        int ke = ks * 32 + koct * 8 + j; int g = ke >> 6, kk = ke & 63;
        float x = (kk < 62) ? Wloc[d * 62 + kk] : 0.0f;
        unsigned short hi = bfh(x);
        pk.us[j] = (g == 2) ? bfh(x - bf2f(hi)) : hi;
      }
      store_pk(WLSW + id * 8, pk);
    }
    // m_proj transposed: MP[b][t][d] = sum_k enc[b][t][k] * Wm[d][k]
    for (int tt = wg; tt < 2048; tt += NWG) {
      int b = tt >> 6, r2 = tt & 63, d0 = (r2 >> 3) * 64, t0 = (r2 & 7) * 64;
      float acc[2][2] = {};
      for (int kc = 0; kc < Dc; kc += 64) {
        __syncthreads();
        for (int i = tid; i < 64 * 64; i += NTH) {
          int rr = i >> 6, kk = i & 63;
          sh.init.tw[rr][kk] = Wm[(size_t)(d0 + rr) * Dc + kc + kk];
          sh.init.ta[rr][kk] = enc[((size_t)b * TENC + t0 + rr) * Dc + kc + kk];
        }
        __syncthreads();
        int tx = tid & 31, ty2 = tid >> 5;
        for (int kk = 0; kk < 64; ++kk) {
          float wv[2], ev[2];
#pragma unroll
          for (int p = 0; p < 2; ++p) { wv[p] = sh.init.tw[ty2 * 2 + p][kk]; ev[p] = sh.init.ta[tx * 2 + p][kk]; }
#pragma unroll
          for (int p = 0; p < 2; ++p)
#pragma unroll
            for (int q2 = 0; q2 < 2; ++q2) acc[p][q2] += wv[p] * ev[q2];
        }
      }
      int tx = tid & 31, ty2 = tid >> 5;
      for (int p = 0; p < 2; ++p)
        for (int q2 = 0; q2 < 2; ++q2)
          stg_(MP + ((size_t)b * TENC + t0 + tx * 2 + q2) * Dc + (d0 + ty2 * 2 + p), acc[p][q2]);
    }
  }

  // ---- T1: MFMA conv + energy + softmax + ctx ----
  auto T1 = [&](int n) {
    const int cur = n & 1, prv = 1 - cur;
    const int b = wg & 31, t0 = (wg >> 5) * 64;
    if (tid < 94) {
      int g = t0 - 15 + tid;
      bool ok = (g >= 0 && g < TENC);
      float rsp = 1.0f / ldg_(S + prv * 32 + b);
      float av = ok ? ldg_(Wb + (size_t)prv * Bc * TENC + b * TENC + g) * rsp : 0.0f;
      float ac = (ok ? ldg_(AC + (size_t)prv * Bc * TENC + b * TENC + g) : 0.0f) + av;
      sh.t1.ain[tid] = av; sh.t1.acin[tid] = ac;
    }
    if (tid < 512) { sh.t1.q[tid] = ldg_(Q + (size_t)b * Dc + tid); sh.t1.v[tid] = v[tid]; }
    __syncthreads();
    if (tid < 64) stg_(AC + (size_t)cur * Bc * TENC + b * TENC + t0 + tid, sh.t1.acin[tid + 15]);
    // build window B-frags into LDS (expanded K: [Bh(62pad64); Bl; Bh])
    auto buildWin = [&](int p) {
      int nt = p / 384, rem = p - nt * 384, l = rem & 63, ks = rem >> 6;
      int ttl = nt * 16 + (l & 15), koct = l >> 4;
      PK8 pk;
#pragma unroll
      for (int j = 0; j < 8; ++j) {
        int ke = ks * 32 + koct * 8 + j; int g = ke >> 6, kk = ke & 63;
        float x = 0.0f;
        if (kk < 31) x = sh.t1.ain[ttl + kk];
        else if (kk < 62) x = sh.t1.acin[ttl + kk - 31];
        unsigned short hi = bfh(x);
        pk.us[j] = (g == 1) ? bfh(x - bf2f(hi)) : hi;
      }
      *(short8*)&sh.t1.win[p * 8] = pk.s8;
    };
    buildWin(tid);
    if (tid < 512) buildWin(1024 + tid);
    __syncthreads();
    // MFMA conv + energy partials
    {
      const int w = tid >> 6, l = tid & 63;
      const short8* WLv = (const short8*)WLSW;
      short8 af[2][6];
#pragma unroll
      for (int mi = 0; mi < 2; ++mi)
#pragma unroll
        for (int ks = 0; ks < 6; ++ks) af[mi][ks] = WLv[(((w * 2 + mi) * 6) + ks) * 64 + l];
      float ep[4] = {0.f, 0.f, 0.f, 0.f};
#pragma unroll 1
      for (int nt = 0; nt < 4; ++nt) {
        short8 bf[6];
#pragma unroll
        for (int ks = 0; ks < 6; ++ks) bf[ks] = *(const short8*)&sh.t1.win[(((nt * 6) + ks) * 64 + l) * 8];
#pragma unroll
        for (int mi = 0; mi < 2; ++mi) {
          f32x4 cc = {0.f, 0.f, 0.f, 0.f};
#pragma unroll
          for (int ks = 0; ks < 6; ++ks) cc = __builtin_amdgcn_mfma_f32_16x16x32_bf16(af[mi][ks], bf[ks], cc, 0, 0, 0);
          int dbase = (w * 2 + mi) * 16 + (l >> 4) * 4;
          int t = t0 + nt * 16 + (l & 15);
          f32x4 qv = *(const f32x4*)&sh.t1.q[dbase];
          f32x4 vv = *(const f32x4*)&sh.t1.v[dbase];
          f32x4 mp4 = *(const f32x4*)(MP + ((size_t)b * TENC + t) * Dc + dbase);
#pragma unroll
          for (int i = 0; i < 4; ++i) ep[nt] += vv[i] * tanhf2(cc[i] + qv[i] + mp4[i]);
        }
      }
#pragma unroll
      for (int nt = 0; nt < 4; ++nt) {
        float e = ep[nt];
        e += __shfl_xor(e, 16);
        e += __shfl_xor(e, 32);
        if ((l >> 4) == 0) sh.t1.ered[w][nt * 16 + l] = e;
      }
    }
    __syncthreads();
    if (tid < 64) {
      float e = 0.0f;
#pragma unroll
      for (int w2 = 0; w2 < 16; ++w2) e += sh.t1.ered[w2][tid];
      float ex = __expf(e);
      stg_(Wb + (size_t)cur * Bc * TENC + b * TENC + t0 + tid, ex);
      sh.t1.we[tid] = ex;
      float sum = ex;
#pragma unroll
      for (int off = 32; off > 0; off >>= 1) sum += __shfl_down(sum, off, 64);
      if (tid == 0) atadd_(S + cur * 32 + b, sum);
    }
    __syncthreads();
    if (tid < 512) {
      float cp = 0.0f;
#pragma unroll 4
      for (int t2 = 0; t2 < 64; ++t2) cp += sh.t1.we[t2] * enc[((size_t)b * TENC + t0 + t2) * Dc + tid];
      atadd_(CT + (size_t)cur * Dc * Bc + tid * Bc + b, cp);
    }
  };

  // ---- XS: build split-bf16 x B-frags for both LSTMs; zero next accumulators ----
  auto XS = [&](int n, bool att_on) {
    const int cur = n & 1, nxt = 1 - cur;
    if (wg < 104) {
      if (att_on && tid < 128) {
        int nt = tid >> 6, l = tid & 63, ks = wg;
        int b = nt * 16 + (l & 15), koct = l >> 4;
        float rs = 1.0f / ldg_(S + cur * 32 + b);
        PK8 pk;
#pragma unroll
        for (int j = 0; j < 8; ++j) {
          int ke = ks * 32 + koct * 8 + j; float x = 0.0f; int g = 0;
          if (ke < 3312) {
            g = ke / 1104; int kk = ke - g * 1104;
            if (kk < 80)       x = MT[(size_t)(n + 1) * MELc * Bc + kk * 32 + b];
            else if (kk < 592) x = ldg_(CT + (size_t)cur * Dc * Bc + (kk - 80) * 32 + b) * rs;
            else               x = ldg_(HA + (size_t)cur * Dc * Bc + (kk - 592) * 32 + b);
          }
          unsigned short hi = bfh(x);
          pk.us[j] = (g == 1) ? bfh(x - bf2f(hi)) : hi;
        }
        store_pk(XSA + ((size_t)(ks * 2 + nt) * 64 + l) * 8, pk);
      }
    } else if (wg < 248) {
      if (n >= 0 && tid < 128) {
        int nt = tid >> 6, l = tid & 63, ks = wg - 104;
        int b = nt * 16 + (l & 15), koct = l >> 4;
        float rs = 1.0f / ldg_(S + cur * 32 + b);
        PK8 pk;
#pragma unroll
        for (int j = 0; j < 8; ++j) {
          int ke = ks * 32 + koct * 8 + j;
          int g = ke / 1536, kk = ke - g * 1536;
          float x;
          if (kk < 512)       x = ldg_(HA + (size_t)cur * Dc * Bc + kk * 32 + b);
          else if (kk < 1024) x = ldg_(CT + (size_t)cur * Dc * Bc + (kk - 512) * 32 + b) * rs;
          else                x = ldg_(HD + (size_t)nxt * Dc * Bc + (kk - 1024) * 32 + b);
          unsigned short hi = bfh(x);
          pk.us[j] = (g == 1) ? bfh(x - bf2f(hi)) : hi;
        }
        store_pk(XSD + ((size_t)(ks * 2 + nt) * 64 + l) * 8, pk);
      }
    } else {
      for (int i = (wg - 248) * NTH + tid; i < Dc * Bc; i += 8 * NTH) stg_(CT + (size_t)nxt * Dc * Bc + i, 0.0f);
      if (wg == 248 && tid < Bc) stg_(S + nxt * 32 + tid, 0.0f);
    }
  };

  // ---- GG: att GEMM (WG 0..127) || dec GEMM (WG 128..255), MFMA + cell update ----
  auto GG = [&](int n, bool att_on) {
    const int cur = n & 1, nxt = 1 - cur;
    const bool is_att = (wg < 128);
    const int m = wg & 127;
    const bool active = is_att ? att_on : (n >= 0);
    const int w = tid >> 6, l = tid & 63;
    if (active) {
      const int nks = is_att ? 104 : 144;
      const short8* Wv = (const short8*)(is_att ? WASW : WDSW);
      const unsigned short* Xp = is_att ? XSA : XSD;
      int ks0, ksn;
      if (is_att) { if (w < 8) { ks0 = w * 7; ksn = 7; } else { ks0 = 56 + (w - 8) * 6; ksn = 6; } }
      else { ks0 = w * 9; ksn = 9; }
      f32x4 acc0 = {0.f, 0.f, 0.f, 0.f}, acc1 = {0.f, 0.f, 0.f, 0.f};
      for (int i = 0; i < ksn; ++i) {
        int ks = ks0 + i;
        short8 a  = Wv[((size_t)m * nks + ks) * 64 + l];
        short8 b0 = load_pk(Xp + ((size_t)(ks * 2 + 0) * 64 + l) * 8);
        short8 b1 = load_pk(Xp + ((size_t)(ks * 2 + 1) * 64 + l) * 8);
        acc0 = __builtin_amdgcn_mfma_f32_16x16x32_bf16(a, b0, acc0, 0, 0, 0);
        acc1 = __builtin_amdgcn_mfma_f32_16x16x32_bf16(a, b1, acc1, 0, 0, 0);
      }
      *(f32x4*)&sh.gg.red[w][0][l][0] = acc0;
      *(f32x4*)&sh.gg.red[w][1][l][0] = acc1;
    }
    __syncthreads();
    if (active && tid < 128) {
      int nt = tid >> 6, l2 = tid & 63;
      float g4[4] = {0.f, 0.f, 0.f, 0.f};
#pragma unroll
      for (int w2 = 0; w2 < 16; ++w2) {
        f32x4 r = *(const f32x4*)&sh.gg.red[w2][nt][l2][0];
        g4[0] += r[0]; g4[1] += r[1]; g4[2] += r[2]; g4[3] += r[3];
      }
      int u = m * 4 + (l2 >> 4), b = nt * 16 + (l2 & 15);
      const float* Bv = is_att ? BA : BD;
#pragma unroll
      for (int ty = 0; ty < 4; ++ty) g4[ty] += ldg_(Bv + u * 4 + ty);
      float* Cst = is_att ? CA : CD;
      float co = ldg_(Cst + u * 32 + b);
      float cn = sigf(g4[1]) * co + sigf(g4[0]) * tanhf2(g4[2]);
      stg_(Cst + u * 32 + b, cn);
      float h = sigf(g4[3]) * tanhf2(cn);
      stg_((is_att ? (HA + (size_t)nxt * Dc * Bc) : (HD + (size_t)cur * Dc * Bc)) + u * 32 + b, h);
    }
  };

  // ---- QM: q projection (VALU) + mel/stop outputs ----
  auto QM = [&](int n) {
    const int cur = n & 1, nxt = 1 - cur;
    if (wg < 64) {
      if (n < TDECc - 1) {
        int b = wg >> 1;
        for (int k = tid; k < Dc; k += NTH) sh.qm.h[k] = ldg_(HA + (size_t)nxt * Dc * Bc + k * Bc + b);
        __syncthreads();
        int ks = tid >> 8, dl = tid & 255, d = (wg & 1) * 256 + dl;
        float acc = 0.0f;
        const int k0 = ks * 128, k1 = k0 + 128;
#pragma unroll 4
        for (int k = k0; k < k1; ++k) acc += WQT[(size_t)k * Dc + d] * sh.qm.h[k];
        sh.qm.part[dl][ks] = acc;
        __syncthreads();
        if (tid < 256)
          stg_(Q + (size_t)b * Dc + (wg & 1) * 256 + tid,
               sh.qm.part[tid][0] + sh.qm.part[tid][1] + sh.qm.part[tid][2] + sh.qm.part[tid][3]);
      }
    } else if (wg < 74) {
      if (n >= 0) {
        int b2 = tid & 31, mq = tid >> 5, ml = mq & 7, ks = mq >> 3;
        int m = (wg - 64) * 8 + ml;
        float acc = (ks == 0) ? bmel[m] : 0.0f;
        const int k0 = ks * 128, k1 = k0 + 128;
#pragma unroll 4
        for (int k = k0; k < k1; ++k) acc += WMT[(size_t)k * MELc + m] * ldg_(HD + (size_t)cur * Dc * Bc + k * Bc + b2);
        sh.qm.part[(ml << 5) | b2][ks] = acc;
        __syncthreads();
        if (tid < 256) {
          int mm = (wg - 64) * 8 + (tid >> 5), bb = tid & 31;
          out[(size_t)bb * TDECc * MELc + (size_t)n * MELc + mm] =
              sh.qm.part[tid][0] + sh.qm.part[tid][1] + sh.qm.part[tid][2] + sh.qm.part[tid][3];
        }
      }
    } else if (wg == 74) {
      if (n >= 0) {
        int b2 = tid & 31, ks = tid >> 5;
        float acc = (ks == 0) ? bstop[0] : 0.0f;
        const int k0 = ks * 16, k1 = k0 + 16;
#pragma unroll 4
        for (int k = k0; k < k1; ++k) acc += Wstop[k] * ldg_(HD + (size_t)cur * Dc * Bc + k * Bc + b2);
        sh.qm.sp[ks][b2] = acc;
        __syncthreads();
        if (tid < 32) {
          float s2 = 0.0f;
#pragma unroll
          for (int i = 0; i < 32; ++i) s2 += sh.qm.sp[i][tid];
          out[(size_t)Bc * TDECc * MELc + (size_t)tid * TDECc + n] = s2;
        }
      }
    }
  };

  // ================= schedule =================
  gbar();
  XS(-1, true);  gbar();   // att x for step 0 (mel0, ctx=0, h=0)
  GG(-1, true);  gbar();   // h_att(0)
  QM(-1);        gbar();   // q(0)
#pragma unroll 1
  for (int n = 0; n < TDECc; ++n) {
    bool att_on = (n < TDECc - 1);
    T1(n);           gbar();
    XS(n, att_on);   gbar();
    GG(n, att_on);   gbar();
    QM(n);           gbar();
  }
}

extern "C" void kernel_launch(void* const* d_in, const int* in_sizes, int n_in,
                              void* d_out, int out_size, void* d_ws, size_t ws_size,
                              hipStream_t stream) {
  (void)in_sizes; (void)n_in; (void)out_size; (void)ws_size;
  const float* enc     = (const float*)d_in[0];
  const float* mel_in  = (const float*)d_in[1];
  const float* Wih_att = (const float*)d_in[2];
  const float* Whh_att = (const float*)d_in[3];
  const float* b_att   = (const float*)d_in[4];
  const float* Wih_dec = (const float*)d_in[5];
  const float* Whh_dec = (const float*)d_in[6];
  const float* b_dec   = (const float*)d_in[7];
  const float* Wq      = (const float*)d_in[8];
  const float* Wm      = (const float*)d_in[9];
  const float* Wloc    = (const float*)d_in[10];
  const float* v       = (const float*)d_in[11];
  const float* Wmel    = (const float*)d_in[12];
  const float* bmel    = (const float*)d_in[13];
  const float* Wstop   = (const float*)d_in[14];
  const float* bstop   = (const float*)d_in[15];
  float* out = (float*)d_out;
  float* ws  = (float*)d_ws;

  hipMemsetAsync(d_ws, 0, ZERO_END * sizeof(float), stream);

  void* args[] = { &enc, &mel_in, &Wih_att, &Whh_att, &b_att, &Wih_dec, &Whh_dec, &b_dec,
                   &Wq, &Wm, &Wloc, &v, &Wmel, &bmel, &Wstop, &bstop, &out, &ws };
  hipLaunchCooperativeKernel((void*)decoder_persist, dim3(NWG), dim3(NTH), args, 0, stream);
}

// Round 5
// 51611.884 us; speedup vs baseline: 3.0576x; 1.3128x over previous
//
#include <hip/hip_runtime.h>

#define DEV __device__ __forceinline__

typedef __attribute__((ext_vector_type(8))) short short8;   // 8 bf16 = 4 VGPR
typedef __attribute__((ext_vector_type(4))) float f32x4;
typedef __attribute__((ext_vector_type(4))) unsigned short us4;

namespace {
constexpr int NWG = 256, NTH = 1024;
constexpr int Bc = 32, TENC = 512, TDECc = 512, Dc = 512, MELc = 80;

// ---- mutable (memset-zeroed) region ----
constexpr size_t OFF_S    = 640;                                 // [2][32] softmax denom
constexpr size_t OFF_W    = OFF_S + 64;                          // [2][32][512] exp(e)
constexpr size_t OFF_ACUM = OFF_W    + (size_t)2 * Bc * TENC;    // [2][32][512]
constexpr size_t OFF_CTXT = OFF_ACUM + (size_t)2 * Bc * TENC;    // [2][512][32] unnormalized ctx^T
constexpr size_t OFF_HATT = OFF_CTXT + (size_t)2 * Dc * Bc;      // [2][512][32]
constexpr size_t OFF_HDEC = OFF_HATT + (size_t)2 * Dc * Bc;      // [2][512][32]
constexpr size_t OFF_CATT = OFF_HDEC + (size_t)2 * Dc * Bc;      // [512][32]
constexpr size_t OFF_CDEC = OFF_CATT + (size_t)Dc * Bc;          // [512][32]
constexpr size_t OFF_Q    = OFF_CDEC + (size_t)Dc * Bc;          // [32][512]
constexpr size_t ZERO_END = OFF_Q    + (size_t)Bc * Dc;
// ---- read-only after INIT / per-step rewritten ----
constexpr size_t OFF_MPROJ = (ZERO_END + 255) & ~(size_t)255;    // fp32 [32][512(t)][512(d)] (init->LDS only)
constexpr size_t OFF_WA2   = OFF_MPROJ + (size_t)Bc * TENC * Dc; // att A-frags [128][70][64][8] bf16 (hi35|lo35)
constexpr size_t OFF_WD2   = OFF_WA2 + (size_t)128*70*64*4;      // dec A-frags [128][96][64][8] (hi48|lo48)
constexpr size_t OFF_WL2   = OFF_WD2 + (size_t)128*96*64*4;      // conv A-frags [32][4][64][8] (hi2|lo2)
constexpr size_t OFF_XSA   = OFF_WL2 + (size_t)32*4*64*4;        // att B-frags [70][2][64][8] (hi35|lo35)
constexpr size_t OFF_XSD   = OFF_XSA + (size_t)70*2*64*4;        // dec B-frags [96][2][64][8]
constexpr size_t OFF_WQT   = OFF_XSD + (size_t)96*2*64*4;        // [512][512] fp32
constexpr size_t OFF_WMELT = OFF_WQT + (size_t)Dc*Dc;            // [512][80]
constexpr size_t OFF_MELT  = OFF_WMELT + (size_t)Dc*MELc;        // [512][80][32]
constexpr size_t OFF_BA    = OFF_MELT + (size_t)TDECc*MELc*Bc;   // [2048] interleaved c=u*4+ty
constexpr size_t OFF_BD    = OFF_BA + 2048;                      // [2048]
} // namespace

// device-coherent (L3-direct) accessors for mutable cross-WG state
DEV float ldg_(const float* p) { return __hip_atomic_load((float*)p, __ATOMIC_RELAXED, __HIP_MEMORY_SCOPE_AGENT); }
DEV void  stg_(float* p, float x) { __hip_atomic_store(p, x, __ATOMIC_RELAXED, __HIP_MEMORY_SCOPE_AGENT); }
DEV unsigned ldgu_(const unsigned* p) { return __hip_atomic_load((unsigned*)p, __ATOMIC_RELAXED, __HIP_MEMORY_SCOPE_AGENT); }
DEV void  stgu_(unsigned* p, unsigned x) { __hip_atomic_store(p, x, __ATOMIC_RELAXED, __HIP_MEMORY_SCOPE_AGENT); }
DEV void  atadd_(float* p, float x) { (void)__hip_atomic_fetch_add(p, x, __ATOMIC_RELAXED, __HIP_MEMORY_SCOPE_AGENT); }
DEV float sigf(float x) { return 1.0f / (1.0f + __expf(-x)); }
DEV float tanhf2(float x) { return 1.0f - 2.0f / (__expf(2.0f * x) + 1.0f); }
DEV unsigned short bfh(float x) { union { float f; unsigned u; } v; v.f = x; unsigned r = v.u + 0x7FFF + ((v.u >> 16) & 1); return (unsigned short)(r >> 16); }
DEV float bf2f(unsigned short h) { union { unsigned u; float f; } v; v.u = (unsigned)h << 16; return v.f; }

union PK8 { unsigned short us[8]; short8 s8; unsigned u[4]; };

DEV void store_pk(unsigned short* dst, const PK8& pk) {
  unsigned* d = (unsigned*)dst;
#pragma unroll
  for (int i = 0; i < 4; ++i) stgu_(d + i, pk.u[i]);
}
DEV short8 load_pk(const unsigned short* src) {
  const unsigned* s = (const unsigned*)src;
  PK8 pk;
#pragma unroll
  for (int i = 0; i < 4; ++i) pk.u[i] = ldgu_(s + i);
  return pk.s8;
}

struct __attribute__((aligned(16))) Lds {
  unsigned short mp[64][520];   // bf16 m_proj slice [t][d], +8 pad vs bank conflicts
  unsigned short en[64][520];   // bf16 enc slice [t][d]
  union {
    struct __attribute__((aligned(16))) {
      unsigned short win[4][4][64][8];  // conv B frags [nt][ks(hi2|lo2)][lane][8]
      float q[512], v[512];
      float ain[96], acin[96];
      float ered[16][64];
      float we[64];
    } t1;                                              // 25,600 B
    struct __attribute__((aligned(16))) { float red[8][2][64][4]; } gg;  // 16,384 B
    struct { float tw[32][33], ta[32][33]; } init;     // 8,448 B
    struct { float h[512]; float part[256][4]; float sp[32][33]; } qm;   // 10,368 B
  } u;
};

__global__ __launch_bounds__(NTH, 4) void decoder_persist(
    const float* __restrict__ enc, const float* __restrict__ mel_in,
    const float* __restrict__ Wih_att, const float* __restrict__ Whh_att, const float* __restrict__ b_att,
    const float* __restrict__ Wih_dec, const float* __restrict__ Whh_dec, const float* __restrict__ b_dec,
    const float* __restrict__ Wq, const float* __restrict__ Wm, const float* __restrict__ Wloc,
    const float* __restrict__ v, const float* __restrict__ Wmel, const float* __restrict__ bmel,
    const float* __restrict__ Wstop, const float* __restrict__ bstop,
    float* __restrict__ out, float* __restrict__ ws)
{
  const int wg = blockIdx.x, tid = threadIdx.x;
  extern __shared__ __align__(16) char smem_raw[];
  Lds& sh = *(Lds*)smem_raw;

  unsigned int* bar = (unsigned int*)(ws);           // gen @0; cells @64+(p*8+i)*32
  float* S  = ws + OFF_S;   float* Wb = ws + OFF_W;   float* AC = ws + OFF_ACUM;
  float* CT = ws + OFF_CTXT; float* HA = ws + OFF_HATT; float* HD = ws + OFF_HDEC;
  float* CA = ws + OFF_CATT; float* CD = ws + OFF_CDEC; float* Q  = ws + OFF_Q;
  float* MP = ws + OFF_MPROJ;
  unsigned short* WA2 = (unsigned short*)(ws + OFF_WA2);
  unsigned short* WD2 = (unsigned short*)(ws + OFF_WD2);
  unsigned short* WL2 = (unsigned short*)(ws + OFF_WL2);
  unsigned short* XSA = (unsigned short*)(ws + OFF_XSA);
  unsigned short* XSD = (unsigned short*)(ws + OFF_XSD);
  float* WQT = ws + OFF_WQT; float* WMT = ws + OFF_WMELT; float* MT = ws + OFF_MELT;
  float* BA = ws + OFF_BA;  float* BD = ws + OFF_BD;

  // ---- grid barrier: 8 padded arrival cells (parity-duplexed) + master poll ----
  auto gbar = [&]() {
    __syncthreads();
    if (tid == 0) {
      unsigned g = __hip_atomic_load(&bar[0], __ATOMIC_RELAXED, __HIP_MEMORY_SCOPE_AGENT);
      unsigned p = g & 1u;
      (void)__hip_atomic_fetch_add(&bar[64 + (p * 8 + (wg & 7)) * 32], 1u, __ATOMIC_RELEASE, __HIP_MEMORY_SCOPE_AGENT);
      if (wg == 0) {
        for (;;) {
          unsigned s = 0;
#pragma unroll
          for (int i = 0; i < 8; ++i)
            s += __hip_atomic_load(&bar[64 + (p * 8 + i) * 32], __ATOMIC_RELAXED, __HIP_MEMORY_SCOPE_AGENT);
          if (s == (unsigned)NWG) break;
          __builtin_amdgcn_s_sleep(2);
        }
#pragma unroll
        for (int i = 0; i < 8; ++i)
          __hip_atomic_store(&bar[64 + (p * 8 + i) * 32], 0u, __ATOMIC_RELAXED, __HIP_MEMORY_SCOPE_AGENT);
        (void)__hip_atomic_fetch_add(&bar[0], 1u, __ATOMIC_RELEASE, __HIP_MEMORY_SCOPE_AGENT);
      } else {
        while (__hip_atomic_load(&bar[0], __ATOMIC_RELAXED, __HIP_MEMORY_SCOPE_AGENT) == g)
          __builtin_amdgcn_s_sleep(4);
      }
    }
    __syncthreads();
  };

  // ================= INIT =================
  {
    for (int k = wg; k < Dc; k += NWG)
      for (int d = tid; d < Dc; d += NTH) stg_(WQT + (size_t)k * Dc + d, Wq[(size_t)d * Dc + k]);
    if (wg == 0)
      for (int i = tid; i < Dc * MELc; i += NTH) { int k = i / MELc, m = i % MELc; stg_(WMT + (size_t)k * MELc + m, Wmel[(size_t)m * Dc + k]); }
    if (wg == 1)
      for (int c = tid; c < 2048; c += NTH) { int u = c >> 2, ty = c & 3; stg_(BA + c, b_att[ty * Dc + u]); stg_(BD + c, b_dec[ty * Dc + u]); }
    if (wg == 2 && tid < Bc) stg_(S + 32 + tid, 1.0f);
    for (int t = wg; t < TDECc; t += NWG)
      for (int i = tid; i < MELc * Bc; i += NTH) {
        int m = i >> 5, b = i & 31;
        stg_(MT + (size_t)t * MELc * Bc + m * Bc + b, mel_in[(size_t)b * TDECc * MELc + (size_t)t * MELc + m]);
      }
    // att A-frags: groups [Ah(35 ks); Al(35 ks)], K=1104 pad 1120
    for (size_t id = (size_t)wg * NTH + tid; id < (size_t)128 * 70 * 64; id += (size_t)NWG * NTH) {
      int l = id & 63; size_t r = id >> 6; int ks = (int)(r % 70); int m = (int)(r / 70);
      int g = (ks >= 35), ksr = ks - (g ? 35 : 0);
      int c = m * 16 + (l & 15), u = c >> 2, ty = c & 3, wrow = ty * 512 + u, koct = l >> 4;
      PK8 pk;
#pragma unroll
      for (int j = 0; j < 8; ++j) {
        int ke = ksr * 32 + koct * 8 + j; float x = 0.0f;
        if (ke < 1104) x = (ke < 592) ? Wih_att[(size_t)wrow * 592 + ke] : Whh_att[(size_t)wrow * 512 + (ke - 592)];
        unsigned short hi = bfh(x);
        pk.us[j] = g ? bfh(x - bf2f(hi)) : hi;
      }
      store_pk(WA2 + id * 8, pk);
    }
    // dec A-frags: groups [Ah(48); Al(48)], K=1536
    for (size_t id = (size_t)wg * NTH + tid; id < (size_t)128 * 96 * 64; id += (size_t)NWG * NTH) {
      int l = id & 63; size_t r = id >> 6; int ks = (int)(r % 96); int m = (int)(r / 96);
      int g = (ks >= 48), ksr = ks - (g ? 48 : 0);
      int c = m * 16 + (l & 15), u = c >> 2, ty = c & 3, wrow = ty * 512 + u, koct = l >> 4;
      PK8 pk;
#pragma unroll
      for (int j = 0; j < 8; ++j) {
        int ke = ksr * 32 + koct * 8 + j;
        float x = (ke < 1024) ? Wih_dec[(size_t)wrow * 1024 + ke] : Whh_dec[(size_t)wrow * 512 + (ke - 1024)];
        unsigned short hi = bfh(x);
        pk.us[j] = g ? bfh(x - bf2f(hi)) : hi;
      }
      store_pk(WD2 + id * 8, pk);
    }
    // conv A-frags: [32 mt][ks: hi{0,1} lo{2,3}][64][8]; K=62 pad 64
    for (size_t id = (size_t)wg * NTH + tid; id < (size_t)32 * 4 * 64; id += (size_t)NWG * NTH) {
      int l = id & 63; size_t r = id >> 6; int ks = (int)(r % 4); int mt = (int)(r / 4);
      int g = (ks >= 2), ks2 = ks & 1;
      int d = mt * 16 + (l & 15), koct = l >> 4;
      PK8 pk;
#pragma unroll
      for (int j = 0; j < 8; ++j) {
        int ke = ks2 * 32 + koct * 8 + j;
        float x = (ke < 62) ? Wloc[d * 62 + ke] : 0.0f;
        unsigned short hi = bfh(x);
        pk.us[j] = g ? bfh(x - bf2f(hi)) : hi;
      }
      store_pk(WL2 + id * 8, pk);
    }
    // m_proj: MP[b][t][d] = sum_k enc[b][t][k] * Wm[d][k]  (32x32 tiles)
    for (int tt = wg; tt < 8192; tt += NWG) {
      int b = tt >> 8, rr = tt & 255, d0 = (rr >> 4) * 32, t0 = (rr & 15) * 32;
      int ty2 = tid >> 5, tx = tid & 31;
      float acc = 0.0f;
      for (int kc = 0; kc < Dc; kc += 32) {
        __syncthreads();
        {
          int rr2 = tid >> 5, kk = tid & 31;
          sh.u.init.tw[rr2][kk] = Wm[(size_t)(d0 + rr2) * Dc + kc + kk];
          sh.u.init.ta[rr2][kk] = enc[((size_t)b * TENC + t0 + rr2) * Dc + kc + kk];
        }
        __syncthreads();
#pragma unroll 8
        for (int kk = 0; kk < 32; ++kk) acc += sh.u.init.tw[ty2][kk] * sh.u.init.ta[tx][kk];
      }
      stg_(MP + ((size_t)b * TENC + t0 + tx) * Dc + d0 + ty2, acc);
      __syncthreads();
    }
  }
  gbar();
  // ---- load persistent LDS slices (WG = (b, tchunk), step-invariant) ----
  {
    const int b = wg & 31, t0 = (wg >> 5) * 64;
    for (int idx = tid; idx < 64 * 512; idx += NTH) {
      int t = idx >> 9, d = idx & 511;
      sh.mp[t][d] = bfh(ldg_(MP + ((size_t)b * TENC + t0 + t) * Dc + d));
      sh.en[t][d] = bfh(enc[((size_t)b * TENC + t0 + t) * Dc + d]);
    }
  }

  // ---- T1: conv MFMA + energy + softmax + ctx (uses LDS mp/en) ----
  auto T1 = [&](int n) {
    const int cur = n & 1, prv = 1 - cur;
    const int b = wg & 31, t0 = (wg >> 5) * 64;
    if (tid < 94) {
      int g = t0 - 15 + tid;
      bool ok = (g >= 0 && g < TENC);
      float rsp = 1.0f / ldg_(S + prv * 32 + b);
      float av = ok ? ldg_(Wb + (size_t)prv * Bc * TENC + b * TENC + g) * rsp : 0.0f;
      float ac = (ok ? ldg_(AC + (size_t)prv * Bc * TENC + b * TENC + g) : 0.0f) + av;
      sh.u.t1.ain[tid] = av; sh.u.t1.acin[tid] = ac;
    }
    if (tid >= 512) sh.u.t1.q[tid - 512] = ldg_(Q + (size_t)b * Dc + (tid - 512));
    if (tid >= 256 && tid < 512) {                 // FIX: cover all 512 entries of v
      int d2 = tid - 256;
      sh.u.t1.v[d2] = v[d2];
      sh.u.t1.v[d2 + 256] = v[d2 + 256];
    }
    __syncthreads();
    if (tid < 64) stg_(AC + (size_t)cur * Bc * TENC + b * TENC + t0 + tid, sh.u.t1.acin[tid + 15]);
    // build ALL conv window B-frags: 1024 threads = 4nt x 4ks x 64l
    {
      int nt = tid >> 8, ks = (tid >> 6) & 3, l = tid & 63;
      int g = (ks >= 2), ks2 = ks & 1;
      int ttl = nt * 16 + (l & 15), koct = l >> 4;
      PK8 pk;
#pragma unroll
      for (int j = 0; j < 8; ++j) {
        int ke = ks2 * 32 + koct * 8 + j;
        float x = 0.0f;
        if (ke < 31) x = sh.u.t1.ain[ttl + ke];
        else if (ke < 62) x = sh.u.t1.acin[ttl + ke - 31];
        unsigned short hi = bfh(x);
        pk.us[j] = g ? bfh(x - bf2f(hi)) : hi;
      }
      *(short8*)&sh.u.t1.win[nt][ks][l][0] = pk.s8;
    }
    __syncthreads();
    // conv MFMA + energy
    {
      const int w = tid >> 6, l = tid & 63;
      const short8* WLv = (const short8*)WL2;
      short8 ah[2][2], al[2][2];
#pragma unroll
      for (int mi = 0; mi < 2; ++mi)
#pragma unroll
        for (int k2 = 0; k2 < 2; ++k2) {
          ah[mi][k2] = WLv[(((w * 2 + mi) * 4) + k2) * 64 + l];
          al[mi][k2] = WLv[(((w * 2 + mi) * 4) + 2 + k2) * 64 + l];
        }
      float ep[4] = {0.f, 0.f, 0.f, 0.f};
#pragma unroll 1
      for (int nt = 0; nt < 4; ++nt) {
        short8 bh0 = *(const short8*)&sh.u.t1.win[nt][0][l][0];
        short8 bh1 = *(const short8*)&sh.u.t1.win[nt][1][l][0];
        short8 bl0 = *(const short8*)&sh.u.t1.win[nt][2][l][0];
        short8 bl1 = *(const short8*)&sh.u.t1.win[nt][3][l][0];
#pragma unroll
        for (int mi = 0; mi < 2; ++mi) {
          f32x4 cc = {0.f, 0.f, 0.f, 0.f};
          cc = __builtin_amdgcn_mfma_f32_16x16x32_bf16(ah[mi][0], bh0, cc, 0, 0, 0);
          cc = __builtin_amdgcn_mfma_f32_16x16x32_bf16(ah[mi][1], bh1, cc, 0, 0, 0);
          cc = __builtin_amdgcn_mfma_f32_16x16x32_bf16(ah[mi][0], bl0, cc, 0, 0, 0);
          cc = __builtin_amdgcn_mfma_f32_16x16x32_bf16(ah[mi][1], bl1, cc, 0, 0, 0);
          cc = __builtin_amdgcn_mfma_f32_16x16x32_bf16(al[mi][0], bh0, cc, 0, 0, 0);
          cc = __builtin_amdgcn_mfma_f32_16x16x32_bf16(al[mi][1], bh1, cc, 0, 0, 0);
          int dbase = (w * 2 + mi) * 16 + (l >> 4) * 4;
          int tloc = nt * 16 + (l & 15);
          us4 mpu = *(const us4*)&sh.mp[tloc][dbase];
          f32x4 qv = *(const f32x4*)&sh.u.t1.q[dbase];
          f32x4 vv = *(const f32x4*)&sh.u.t1.v[dbase];
#pragma unroll
          for (int i = 0; i < 4; ++i) ep[nt] += vv[i] * tanhf2(cc[i] + qv[i] + bf2f(mpu[i]));
        }
      }
#pragma unroll
      for (int nt = 0; nt < 4; ++nt) {
        float e = ep[nt];
        e += __shfl_xor(e, 16);
        e += __shfl_xor(e, 32);
        if ((l >> 4) == 0) sh.u.t1.ered[w][nt * 16 + l] = e;
      }
    }
    __syncthreads();
    if (tid < 64) {
      float e = 0.0f;
#pragma unroll
      for (int w2 = 0; w2 < 16; ++w2) e += sh.u.t1.ered[w2][tid];
      float ex = __expf(e);
      stg_(Wb + (size_t)cur * Bc * TENC + b * TENC + t0 + tid, ex);
      sh.u.t1.we[tid] = ex;
      float sum = ex;
#pragma unroll
      for (int off = 32; off > 0; off >>= 1) sum += __shfl_down(sum, off, 64);
      if (tid == 0) atadd_(S + cur * 32 + b, sum);
    }
    __syncthreads();
    if (tid < 512) {
      float cp = 0.0f;
#pragma unroll 4
      for (int t2 = 0; t2 < 64; ++t2) cp += sh.u.t1.we[t2] * bf2f(sh.en[t2][tid]);
      atadd_(CT + (size_t)cur * Dc * Bc + tid * Bc + b, cp);
    }
  };

  // ---- XS: build B-frags (hi+lo) for both LSTM GEMMs; zero next accumulators ----
  auto XS = [&](int n, bool att_on) {
    const int cur = n & 1, nxt = 1 - cur;
    if (wg < 35) {                       // att ks = wg
      if (att_on && tid < 512) {
        int ks = wg, b = tid & 31, kp = tid >> 5;
        int kloc = kp * 2, koct = kloc >> 3, jj = kloc & 7;
        int l = koct * 16 + (b & 15), nt = b >> 4;
        float rs = 1.0f / ldg_(S + cur * 32 + b);
        unsigned short h2[2], l2v[2];
#pragma unroll
        for (int q2 = 0; q2 < 2; ++q2) {
          int ke = ks * 32 + kloc + q2; float x = 0.0f;
          if (ke < 1104) {
            if (ke < 80)       x = MT[(size_t)(n + 1) * MELc * Bc + ke * 32 + b];
            else if (ke < 592) x = ldg_(CT + (size_t)cur * Dc * Bc + (ke - 80) * 32 + b) * rs;
            else               x = ldg_(HA + (size_t)cur * Dc * Bc + (ke - 592) * 32 + b);
          }
          unsigned short hi = bfh(x);
          h2[q2] = hi; l2v[q2] = bfh(x - bf2f(hi));
        }
        unsigned ph = (unsigned)h2[0] | ((unsigned)h2[1] << 16);
        unsigned pl = (unsigned)l2v[0] | ((unsigned)l2v[1] << 16);
        stgu_((unsigned*)(XSA + ((size_t)(ks * 2 + nt) * 64 + l) * 8 + jj), ph);
        stgu_((unsigned*)(XSA + ((size_t)((35 + ks) * 2 + nt) * 64 + l) * 8 + jj), pl);
      }
    } else if (wg < 83) {                // dec ks = wg - 35
      if (n >= 0 && tid < 512) {
        int ks = wg - 35, b = tid & 31, kp = tid >> 5;
        int kloc = kp * 2, koct = kloc >> 3, jj = kloc & 7;
        int l = koct * 16 + (b & 15), nt = b >> 4;
        float rs = 1.0f / ldg_(S + cur * 32 + b);
        unsigned short h2[2], l2v[2];
#pragma unroll
        for (int q2 = 0; q2 < 2; ++q2) {
          int ke = ks * 32 + kloc + q2; float x;
          if (ke < 512)       x = ldg_(HA + (size_t)cur * Dc * Bc + ke * 32 + b);
          else if (ke < 1024) x = ldg_(CT + (size_t)cur * Dc * Bc + (ke - 512) * 32 + b) * rs;
          else                x = ldg_(HD + (size_t)nxt * Dc * Bc + (ke - 1024) * 32 + b);
          unsigned short hi = bfh(x);
          h2[q2] = hi; l2v[q2] = bfh(x - bf2f(hi));
        }
        unsigned ph = (unsigned)h2[0] | ((unsigned)h2[1] << 16);
        unsigned pl = (unsigned)l2v[0] | ((unsigned)l2v[1] << 16);
        stgu_((unsigned*)(XSD + ((size_t)(ks * 2 + nt) * 64 + l) * 8 + jj), ph);
        stgu_((unsigned*)(XSD + ((size_t)((48 + ks) * 2 + nt) * 64 + l) * 8 + jj), pl);
      }
    } else if (wg < 91) {
      for (int i = (wg - 83) * NTH + tid; i < Dc * Bc; i += 8 * NTH) stg_(CT + (size_t)nxt * Dc * Bc + i, 0.0f);
      if (wg == 83 && tid < Bc) stg_(S + nxt * 32 + tid, 0.0f);
    }
  };

  // ---- GG: att GEMM (WG 0..127) || dec GEMM (WG 128..255) ----
  auto GG = [&](int n, bool att_on) {
    const int cur = n & 1, nxt = 1 - cur;
    const bool is_att = (wg < 128);
    const int m = wg & 127;
    const bool active = is_att ? att_on : (n >= 0);
    const int w = tid >> 6, l = tid & 63;
    f32x4 acc0 = {0.f, 0.f, 0.f, 0.f}, acc1 = {0.f, 0.f, 0.f, 0.f};
    if (active) {
      const int P = is_att ? 35 : 48, NK = is_att ? 70 : 96;
      const short8* Wv = (const short8*)(is_att ? WA2 : WD2);
      const unsigned short* Xp = is_att ? XSA : XSD;
      for (int i = w; i < P; i += 16) {
        short8 ah = Wv[((size_t)m * NK + i) * 64 + l];
        short8 al = Wv[((size_t)m * NK + P + i) * 64 + l];
        short8 bh0 = load_pk(Xp + ((size_t)(i * 2 + 0) * 64 + l) * 8);
        short8 bh1 = load_pk(Xp + ((size_t)(i * 2 + 1) * 64 + l) * 8);
        short8 bl0 = load_pk(Xp + ((size_t)((P + i) * 2 + 0) * 64 + l) * 8);
        short8 bl1 = load_pk(Xp + ((size_t)((P + i) * 2 + 1) * 64 + l) * 8);
        acc0 = __builtin_amdgcn_mfma_f32_16x16x32_bf16(ah, bh0, acc0, 0, 0, 0);
        acc0 = __builtin_amdgcn_mfma_f32_16x16x32_bf16(ah, bl0, acc0, 0, 0, 0);
        acc0 = __builtin_amdgcn_mfma_f32_16x16x32_bf16(al, bh0, acc0, 0, 0, 0);
        acc1 = __builtin_amdgcn_mfma_f32_16x16x32_bf16(ah, bh1, acc1, 0, 0, 0);
        acc1 = __builtin_amdgcn_mfma_f32_16x16x32_bf16(ah, bl1, acc1, 0, 0, 0);
        acc1 = __builtin_amdgcn_mfma_f32_16x16x32_bf16(al, bh1, acc1, 0, 0, 0);
      }
    }
    if (active && w < 8) { *(f32x4*)&sh.u.gg.red[w][0][l][0] = acc0; *(f32x4*)&sh.u.gg.red[w][1][l][0] = acc1; }
    __syncthreads();
    if (active && w >= 8) {
      f32x4 r0 = *(const f32x4*)&sh.u.gg.red[w - 8][0][l][0];
      f32x4 r1 = *(const f32x4*)&sh.u.gg.red[w - 8][1][l][0];
      *(f32x4*)&sh.u.gg.red[w - 8][0][l][0] = r0 + acc0;
      *(f32x4*)&sh.u.gg.red[w - 8][1][l][0] = r1 + acc1;
    }
    __syncthreads();
    if (active && tid < 128) {
      int nt = tid >> 6, l2 = tid & 63;
      float g4[4] = {0.f, 0.f, 0.f, 0.f};
#pragma unroll
      for (int w2 = 0; w2 < 8; ++w2) {
        f32x4 r = *(const f32x4*)&sh.u.gg.red[w2][nt][l2][0];
        g4[0] += r[0]; g4[1] += r[1]; g4[2] += r[2]; g4[3] += r[3];
      }
      int u = m * 4 + (l2 >> 4), b = nt * 16 + (l2 & 15);
      const float* Bv = is_att ? BA : BD;
#pragma unroll
      for (int ty = 0; ty < 4; ++ty) g4[ty] += ldg_(Bv + u * 4 + ty);
      float* Cst = is_att ? CA : CD;
      float co = ldg_(Cst + u * 32 + b);
      float cn = sigf(g4[1]) * co + sigf(g4[0]) * tanhf2(g4[2]);
      stg_(Cst + u * 32 + b, cn);
      float h = sigf(g4[3]) * tanhf2(cn);
      stg_((is_att ? (HA + (size_t)nxt * Dc * Bc) : (HD + (size_t)cur * Dc * Bc)) + u * 32 + b, h);
    }
  };

  // ---- QM: q projection + mel/stop outputs ----
  auto QM = [&](int n) {
    const int cur = n & 1, nxt = 1 - cur;
    if (wg < 64) {
      if (n < TDECc - 1) {
        int b = wg >> 1;
        for (int k = tid; k < Dc; k += NTH) sh.u.qm.h[k] = ldg_(HA + (size_t)nxt * Dc * Bc + k * Bc + b);
        __syncthreads();
        int ks = tid >> 8, dl = tid & 255, d = (wg & 1) * 256 + dl;
        float acc = 0.0f;
        const int k0 = ks * 128, k1 = k0 + 128;
#pragma unroll 4
        for (int k = k0; k < k1; ++k) acc += WQT[(size_t)k * Dc + d] * sh.u.qm.h[k];
        sh.u.qm.part[dl][ks] = acc;
        __syncthreads();
        if (tid < 256)
          stg_(Q + (size_t)b * Dc + (wg & 1) * 256 + tid,
               sh.u.qm.part[tid][0] + sh.u.qm.part[tid][1] + sh.u.qm.part[tid][2] + sh.u.qm.part[tid][3]);
      }
    } else if (wg < 74) {
      if (n >= 0) {
        int b2 = tid & 31, mq = tid >> 5, ml = mq & 7, ks = mq >> 3;
        int m = (wg - 64) * 8 + ml;
        float acc = (ks == 0) ? bmel[m] : 0.0f;
        const int k0 = ks * 128, k1 = k0 + 128;
#pragma unroll 4
        for (int k = k0; k < k1; ++k) acc += WMT[(size_t)k * MELc + m] * ldg_(HD + (size_t)cur * Dc * Bc + k * Bc + b2);
        sh.u.qm.part[(ml << 5) | b2][ks] = acc;
        __syncthreads();
        if (tid < 256) {
          int mm = (wg - 64) * 8 + (tid >> 5), bb = tid & 31;
          out[(size_t)bb * TDECc * MELc + (size_t)n * MELc + mm] =
              sh.u.qm.part[tid][0] + sh.u.qm.part[tid][1] + sh.u.qm.part[tid][2] + sh.u.qm.part[tid][3];
        }
      }
    } else if (wg == 74) {
      if (n >= 0) {
        int b2 = tid & 31, ks = tid >> 5;
        float acc = (ks == 0) ? bstop[0] : 0.0f;
        const int k0 = ks * 16, k1 = k0 + 16;
#pragma unroll 4
        for (int k = k0; k < k1; ++k) acc += Wstop[k] * ldg_(HD + (size_t)cur * Dc * Bc + k * Bc + b2);
        sh.u.qm.sp[ks][b2] = acc;
        __syncthreads();
        if (tid < 32) {
          float s2 = 0.0f;
#pragma unroll
          for (int i = 0; i < 32; ++i) s2 += sh.u.qm.sp[i][tid];
          out[(size_t)Bc * TDECc * MELc + (size_t)tid * TDECc + n] = s2;
        }
      }
    }
  };

  // ================= schedule =================
  gbar();
  XS(-1, true);  gbar();   // att x for step 0 (mel0, ctx=0, h=0)
  GG(-1, true);  gbar();   // h_att(0)
  QM(-1);        gbar();   // q(0)
#pragma unroll 1
  for (int n = 0; n < TDECc; ++n) {
    bool att_on = (n < TDECc - 1);
    T1(n);           gbar();
    XS(n, att_on);   gbar();
    GG(n, att_on);   gbar();
    QM(n);           gbar();
  }
}

extern "C" void kernel_launch(void* const* d_in, const int* in_sizes, int n_in,
                              void* d_out, int out_size, void* d_ws, size_t ws_size,
                              hipStream_t stream) {
  (void)in_sizes; (void)n_in; (void)out_size; (void)ws_size;
  const float* enc     = (const float*)d_in[0];
  const float* mel_in  = (const float*)d_in[1];
  const float* Wih_att = (const float*)d_in[2];
  const float* Whh_att = (const float*)d_in[3];
  const float* b_att   = (const float*)d_in[4];
  const float* Wih_dec = (const float*)d_in[5];
  const float* Whh_dec = (const float*)d_in[6];
  const float* b_dec   = (const float*)d_in[7];
  const float* Wq      = (const float*)d_in[8];
  const float* Wm      = (const float*)d_in[9];
  const float* Wloc    = (const float*)d_in[10];
  const float* v       = (const float*)d_in[11];
  const float* Wmel    = (const float*)d_in[12];
  const float* bmel    = (const float*)d_in[13];
  const float* Wstop   = (const float*)d_in[14];
  const float* bstop   = (const float*)d_in[15];
  float* out = (float*)d_out;
  float* ws  = (float*)d_ws;

  hipMemsetAsync(d_ws, 0, ZERO_END * sizeof(float), stream);

  const int lds_bytes = (int)sizeof(Lds);   // ~158.7 KB, needs dynamic-LDS opt-in
  (void)hipFuncSetAttribute((const void*)decoder_persist,
                            hipFuncAttributeMaxDynamicSharedMemorySize, lds_bytes);

  void* args[] = { &enc, &mel_in, &Wih_att, &Whh_att, &b_att, &Wih_dec, &Whh_dec, &b_dec,
                   &Wq, &Wm, &Wloc, &v, &Wmel, &bmel, &Wstop, &bstop, &out, &ws };
  hipLaunchCooperativeKernel((void*)decoder_persist, dim3(NWG), dim3(NTH), args,
                             (size_t)lds_bytes, stream);
}